// Round 2
// baseline (1135.857 us; speedup 1.0000x reference)
//
#include <hip/hip_runtime.h>

// KNN (k=5, LARGEST distances per faithful-to-source quirk) + gather-mean.
// x: [B=2048, 64] f32, target: [N=50000, 64] f32, out: [B, 64] f32.
//
// Ranking key: r2 = ||t||^2 - 2*<x,t>  (d2 minus the per-query constant ||x||^2
// -> identical ordering per query, fewer registers).

constexpr int KNN = 5;
constexpr int DD  = 64;   // feature dim
constexpr int QB  = 64;   // queries per block (kernel B)
constexpr int TQ  = 8;    // queries per wave
constexpr int NT  = 256;  // targets per tile
constexpr int KC  = 16;   // d-depth per staged chunk
constexpr int CH  = 16;   // target chunks (grid.x of kernel B)
constexpr int BLK = 512;  // threads in kernel B

// rank (ad,ai) above (bd,bi): larger key first, tie -> smaller index
__device__ __forceinline__ bool pair_gt(float ad, int ai, float bd, int bi) {
  return (ad > bd) || (ad == bd && ai < bi);
}

// Branchless sorted insert into a descending top-5 (caller guarantees the
// candidate ranks above slot 4). All slot reads happen before overwrite.
__device__ __forceinline__ void top5_insert(float d2, int idx,
    float& t0d, float& t1d, float& t2d, float& t3d, float& t4d,
    int&   t0i, int&   t1i, int&   t2i, int&   t3i, int&   t4i) {
  const bool b3 = pair_gt(d2, idx, t3d, t3i);
  const bool b2 = pair_gt(d2, idx, t2d, t2i);
  const bool b1 = pair_gt(d2, idx, t1d, t1i);
  const bool b0 = pair_gt(d2, idx, t0d, t0i);
  t4d = b3 ? t3d : d2;               t4i = b3 ? t3i : idx;
  t3d = b3 ? (b2 ? t2d : d2) : t3d;  t3i = b3 ? (b2 ? t2i : idx) : t3i;
  t2d = b2 ? (b1 ? t1d : d2) : t2d;  t2i = b2 ? (b1 ? t1i : idx) : t2i;
  t1d = b1 ? (b0 ? t0d : d2) : t1d;  t1i = b1 ? (b0 ? t0i : idx) : t1i;
  t0d = b0 ? d2 : t0d;               t0i = b0 ? idx : t0i;
}

// ---------------- Kernel A: per-target squared norm (padded to Npad) ----------------
__launch_bounds__(256)
__global__ void sqnorm_kernel(const float* __restrict__ tg,
                              float* __restrict__ t2, int N, int Npad) {
  const int tid  = threadIdx.x;
  const int lane = tid & 63;
  const int wv   = tid >> 6;
  const int row  = blockIdx.x * 16 + wv * 4 + (lane >> 4);
  const int f4   = lane & 15;
  if (row >= Npad) return;
  float s = 0.0f;
  if (row < N) {
    const float4 v = reinterpret_cast<const float4*>(tg)[(size_t)row * 16 + f4];
    s = v.x*v.x + v.y*v.y + v.z*v.z + v.w*v.w;
    s += __shfl_xor(s, 1);
    s += __shfl_xor(s, 2);
    s += __shfl_xor(s, 4);
    s += __shfl_xor(s, 8);
  }
  if (f4 == 0) t2[row] = s;
}

// ---------------- Kernel B: distances + per-(query,chunk) top-5 ----------------
__launch_bounds__(BLK)   // no occupancy clamp: ~150 live regs, must not spill
__global__ void knn_partial_kernel(const float* __restrict__ x,
                                   const float* __restrict__ tg,
                                   const float* __restrict__ t2w,
                                   float* __restrict__ pd,
                                   int*   __restrict__ pi,
                                   int N) {
  __shared__ float tbuf[2][KC][NT];  // 32 KiB, d-major target tile, double-buffered

  const int tid  = threadIdx.x;
  const int lane = tid & 63;
  const int w    = __builtin_amdgcn_readfirstlane(tid >> 6);  // wave id, uniform
  const int ci   = blockIdx.x;                                // target chunk
  const int q0   = blockIdx.y * QB + w * TQ;                  // wave's first query
  const float* xq = x + (size_t)q0 * DD;                      // wave-uniform base

  // per-thread top-5 per query (descending), key = t2 - 2*dot
  float td0[TQ], td1[TQ], td2[TQ], td3[TQ], td4[TQ];
  int   ti0[TQ], ti1[TQ], ti2[TQ], ti3[TQ], ti4[TQ];
  #pragma unroll
  for (int qi = 0; qi < TQ; ++qi) {
    td0[qi]=td1[qi]=td2[qi]=td3[qi]=td4[qi] = -1e30f;
    ti0[qi]=ti1[qi]=ti2[qi]=ti3[qi]=ti4[qi] = 0;
  }

  float acc[TQ][4];

  const int total_tiles = (N + NT - 1) / NT;
  const int mytiles = (ci < total_tiles) ? ((total_tiles - 1 - ci) / CH + 1) : 0;
  const int C = mytiles * 4;  // chunk iterations

  // staging registers (issue-early / write-late split)
  float4 sva = make_float4(0,0,0,0), svb = make_float4(0,0,0,0);
  const int n0  = tid & 255;          // this thread's target row in tile
  const int j40 = tid >> 8;           // float4 slot 0..1
  const int j41 = j40 + 2;            // float4 slot 2..3
  const float4* tgv = reinterpret_cast<const float4*>(tg);

  // ---- prologue: stage chunk 0 ----
  if (C > 0) {
    const long r0 = (long)ci * NT + n0;
    if (r0 < N) {
      sva = tgv[r0 * 16 + j40];
      svb = tgv[r0 * 16 + j41];
    }
    tbuf[0][j40*4+0][n0] = sva.x;  tbuf[0][j40*4+1][n0] = sva.y;
    tbuf[0][j40*4+2][n0] = sva.z;  tbuf[0][j40*4+3][n0] = sva.w;
    tbuf[0][j41*4+0][n0] = svb.x;  tbuf[0][j41*4+1][n0] = svb.y;
    tbuf[0][j41*4+2][n0] = svb.z;  tbuf[0][j41*4+3][n0] = svb.w;
  }
  __syncthreads();

  for (int c = 0; c < C; ++c) {
    const int b       = c & 1;
    const int kc      = c & 3;
    const int tileidx = ci + (c >> 2) * CH;
    const bool more   = (c + 1 < C);

    // 1) issue global loads for chunk c+1 (latency hides under compute)
    if (more) {
      const int gc2   = c + 1;
      const int kc2   = gc2 & 3;
      const int tile2 = ci + (gc2 >> 2) * CH;
      const long r0n  = (long)tile2 * NT + n0;
      sva = make_float4(0,0,0,0);
      svb = make_float4(0,0,0,0);
      if (r0n < N) {
        sva = tgv[r0n * 16 + kc2 * 4 + j40];
        svb = tgv[r0n * 16 + kc2 * 4 + j41];
      }
    }

    // 2) compute chunk c
    if (kc == 0) {
      #pragma unroll
      for (int qi = 0; qi < TQ; ++qi) {
        acc[qi][0]=0.f; acc[qi][1]=0.f; acc[qi][2]=0.f; acc[qi][3]=0.f;
      }
    }
    #pragma unroll
    for (int h = 0; h < 2; ++h) {
      #pragma unroll
      for (int dd = 0; dd < 8; ++dd) {
        const int dglob = kc * KC + h * 8 + dd;   // uniform runtime offset -> s_load
        float qd[TQ];
        #pragma unroll
        for (int qi = 0; qi < TQ; ++qi) qd[qi] = xq[qi * DD + dglob];
        const float4 tv = *reinterpret_cast<const float4*>(&tbuf[b][h*8+dd][lane*4]);
        #pragma unroll
        for (int qi = 0; qi < TQ; ++qi) {
          acc[qi][0] = fmaf(qd[qi], tv.x, acc[qi][0]);
          acc[qi][1] = fmaf(qd[qi], tv.y, acc[qi][1]);
          acc[qi][2] = fmaf(qd[qi], tv.z, acc[qi][2]);
          acc[qi][3] = fmaf(qd[qi], tv.w, acc[qi][3]);
        }
      }
    }

    // 3) tile epilogue: key = t2 - 2*dot, update top-5
    if (kc == 3) {
      const int nb = tileidx * NT + lane * 4;
      const float4 t2v = *reinterpret_cast<const float4*>(t2w + nb);  // t2w padded
      const float t2a[4] = { t2v.x, t2v.y, t2v.z, t2v.w };
      #pragma unroll
      for (int qi = 0; qi < TQ; ++qi) {
        #pragma unroll
        for (int j = 0; j < 4; ++j) {
          const float r2  = fmaf(-2.0f, acc[qi][j], t2a[j]);
          const int   idx = nb + j;
          if (idx < N && pair_gt(r2, idx, td4[qi], ti4[qi]))
            top5_insert(r2, idx,
                        td0[qi], td1[qi], td2[qi], td3[qi], td4[qi],
                        ti0[qi], ti1[qi], ti2[qi], ti3[qi], ti4[qi]);
        }
      }
    }

    // 4) write staged chunk c+1 into the other buffer
    if (more) {
      const int bo = (c + 1) & 1;
      tbuf[bo][j40*4+0][n0] = sva.x;  tbuf[bo][j40*4+1][n0] = sva.y;
      tbuf[bo][j40*4+2][n0] = sva.z;  tbuf[bo][j40*4+3][n0] = sva.w;
      tbuf[bo][j41*4+0][n0] = svb.x;  tbuf[bo][j41*4+1][n0] = svb.y;
      tbuf[bo][j41*4+2][n0] = svb.z;  tbuf[bo][j41*4+3][n0] = svb.w;
    }
    __syncthreads();
  }

  // ---- cross-lane merge: wave top-5 per query, write partials ----
  #pragma unroll
  for (int qi = 0; qi < TQ; ++qi) {
    float rd[KNN]; int ri[KNN];
    #pragma unroll
    for (int r = 0; r < KNN; ++r) {
      float md = td0[qi]; int mi = ti0[qi];
      #pragma unroll
      for (int k = 1; k < 64; k <<= 1) {
        const float od = __shfl_xor(md, k);
        const int   oi = __shfl_xor(mi, k);
        if (pair_gt(od, oi, md, mi)) { md = od; mi = oi; }
      }
      rd[r] = md; ri[r] = mi;
      if (ti0[qi] == mi && td0[qi] == md) {  // consume winner (indices unique)
        td0[qi]=td1[qi]; ti0[qi]=ti1[qi];
        td1[qi]=td2[qi]; ti1[qi]=ti2[qi];
        td2[qi]=td3[qi]; ti2[qi]=ti3[qi];
        td3[qi]=td4[qi]; ti3[qi]=ti4[qi];
        td4[qi]=-1e30f;  ti4[qi]=0;
      }
    }
    if (lane == 0) {
      const int pbase = (q0 + qi) * (CH * KNN) + ci * KNN;
      #pragma unroll
      for (int r = 0; r < KNN; ++r) { pd[pbase + r] = rd[r]; pi[pbase + r] = ri[r]; }
    }
  }
}

// ---------------- Kernel C: merge partials, gather, mean ----------------
__launch_bounds__(64)
__global__ void merge_kernel(const float* __restrict__ tg,
                             const float* __restrict__ pd,
                             const int*   __restrict__ pi,
                             float* __restrict__ out, int chn) {
  const int q    = blockIdx.x;
  const int lane = threadIdx.x;   // 64 threads
  const int M    = chn * KNN;     // 80 candidates
  const int pb   = q * M;
  float c0d = -1e30f, c1d = -1e30f;
  int   c0i = 0,      c1i = 0;
  if (lane < M)      { c0d = pd[pb + lane];      c0i = pi[pb + lane]; }
  if (lane + 64 < M) { c1d = pd[pb + lane + 64]; c1i = pi[pb + lane + 64]; }
  if (pair_gt(c1d, c1i, c0d, c0i)) {
    const float tdm = c0d; const int tim = c0i;
    c0d = c1d; c0i = c1i; c1d = tdm; c1i = tim;
  }
  int sel[KNN];
  #pragma unroll
  for (int r = 0; r < KNN; ++r) {
    float md = c0d; int mi = c0i;
    #pragma unroll
    for (int k = 1; k < 64; k <<= 1) {
      const float od = __shfl_xor(md, k);
      const int   oi = __shfl_xor(mi, k);
      if (pair_gt(od, oi, md, mi)) { md = od; mi = oi; }
    }
    sel[r] = mi;
    if (c0i == mi && c0d == md) { c0d = c1d; c0i = c1i; c1d = -1e30f; c1i = 0; }
  }
  float s = 0.0f;
  #pragma unroll
  for (int r = 0; r < KNN; ++r) s += tg[(size_t)sel[r] * DD + lane];
  out[(size_t)q * DD + lane] = s / 5.0f;
}

// ---------------- Fallback (only if workspace too small) ----------------
__launch_bounds__(256)
__global__ void knn_fallback(const float* __restrict__ x,
                             const float* __restrict__ tg,
                             float* __restrict__ out, int N) {
  const int q   = blockIdx.x;
  const int tid = threadIdx.x;
  __shared__ float qsh[DD];
  __shared__ float smd[KNN][256];
  __shared__ int   smi[KNN][256];
  if (tid < DD) qsh[tid] = x[(size_t)q * DD + tid];
  __syncthreads();
  float qv[DD];
  #pragma unroll
  for (int d = 0; d < DD; ++d) qv[d] = qsh[d];
  float x2 = 0.0f;
  #pragma unroll
  for (int d = 0; d < DD; ++d) x2 = fmaf(qv[d], qv[d], x2);
  float a0=-1e30f,a1=-1e30f,a2=-1e30f,a3=-1e30f,a4=-1e30f;
  int   i0=0,i1=0,i2=0,i3=0,i4=0;
  for (int n = tid; n < N; n += 256) {
    const float4* tr = reinterpret_cast<const float4*>(tg + (size_t)n * DD);
    float dot = 0.0f, tt = 0.0f;
    #pragma unroll
    for (int k = 0; k < 16; ++k) {
      const float4 tv = tr[k];
      dot = fmaf(qv[4*k+0], tv.x, dot); tt = fmaf(tv.x, tv.x, tt);
      dot = fmaf(qv[4*k+1], tv.y, dot); tt = fmaf(tv.y, tv.y, tt);
      dot = fmaf(qv[4*k+2], tv.z, dot); tt = fmaf(tv.z, tv.z, tt);
      dot = fmaf(qv[4*k+3], tv.w, dot); tt = fmaf(tv.w, tv.w, tt);
    }
    const float d2 = fmaf(-2.0f, dot, x2 + tt);
    if (pair_gt(d2, n, a4, i4))
      top5_insert(d2, n, a0,a1,a2,a3,a4, i0,i1,i2,i3,i4);
  }
  smd[0][tid]=a0; smi[0][tid]=i0;  smd[1][tid]=a1; smi[1][tid]=i1;
  smd[2][tid]=a2; smi[2][tid]=i2;  smd[3][tid]=a3; smi[3][tid]=i3;
  smd[4][tid]=a4; smi[4][tid]=i4;
  __syncthreads();
  if (tid < 64) {
    a0=a1=a2=a3=a4=-1e30f; i0=i1=i2=i3=i4=0;
    for (int src = tid; src < 256; src += 64) {
      #pragma unroll
      for (int r = 0; r < KNN; ++r) {
        const float dd2 = smd[r][src]; const int ii = smi[r][src];
        if (pair_gt(dd2, ii, a4, i4))
          top5_insert(dd2, ii, a0,a1,a2,a3,a4, i0,i1,i2,i3,i4);
      }
    }
    int sel[KNN];
    #pragma unroll
    for (int r = 0; r < KNN; ++r) {
      float md = a0; int mi = i0;
      #pragma unroll
      for (int k = 1; k < 64; k <<= 1) {
        const float od = __shfl_xor(md, k);
        const int   oi = __shfl_xor(mi, k);
        if (pair_gt(od, oi, md, mi)) { md = od; mi = oi; }
      }
      sel[r] = mi;
      if (i0 == mi && a0 == md) {
        a0=a1; i0=i1; a1=a2; i1=i2; a2=a3; i2=i3; a3=a4; i3=i4; a4=-1e30f; i4=0;
      }
    }
    float s = 0.0f;
    #pragma unroll
    for (int r = 0; r < KNN; ++r) s += tg[(size_t)sel[r] * DD + tid];
    out[(size_t)q * DD + tid] = s / 5.0f;
  }
}

extern "C" void kernel_launch(void* const* d_in, const int* in_sizes, int n_in,
                              void* d_out, int out_size, void* d_ws, size_t ws_size,
                              hipStream_t stream) {
  const float* x  = (const float*)d_in[0];
  const float* tg = (const float*)d_in[1];
  float* out = (float*)d_out;
  const int B = in_sizes[0] / DD;   // 2048
  const int N = in_sizes[1] / DD;   // 50000

  const int    Npad     = (N + NT - 1) & ~(NT - 1);   // pad to tile multiple (50176)
  const size_t t2_elems = (size_t)Npad;
  const size_t npart    = (size_t)B * CH * KNN;
  const size_t need     = (t2_elems + 2 * npart) * sizeof(float);

  if (ws_size >= need && (B % QB) == 0) {
    float* t2 = (float*)d_ws;
    float* pd = t2 + t2_elems;
    int*   pi = (int*)(pd + npart);
    sqnorm_kernel<<<dim3(Npad / 16), dim3(256), 0, stream>>>(tg, t2, N, Npad);
    knn_partial_kernel<<<dim3(CH, B / QB), dim3(BLK), 0, stream>>>(x, tg, t2, pd, pi, N);
    merge_kernel<<<dim3(B), dim3(64), 0, stream>>>(tg, pd, pi, out, CH);
  } else {
    knn_fallback<<<dim3(B), dim3(256), 0, stream>>>(x, tg, out, N);
  }
}

// Round 3
// 741.744 us; speedup vs baseline: 1.5313x; 1.5313x over previous
//
#include <hip/hip_runtime.h>

// KNN (k=5, LARGEST distances per faithful-to-source quirk) + gather-mean.
// x: [B=2048, 64] f32, target: [N=50000, 64] f32, out: [B, 64] f32.
//
// Ranking key: r2 = ||t||^2 - 2*<x,t>  (d2 minus the per-query constant ||x||^2
// -> identical ordering per query, fewer registers).
//
// TQ=4 (not 8): keeps live VGPRs ~110 < the 128 cap the allocator picks for
// 512-thread blocks; at TQ=8 (~145 live) it spilled ~2 GB of scratch per
// dispatch (round-1/2 counters: WRITE_SIZE 1.2-1.4 GB vs 1.3 MB legit writes).

constexpr int KNN = 5;
constexpr int DD  = 64;   // feature dim
constexpr int TQ  = 4;    // queries per wave
constexpr int QB  = 32;   // queries per block = 8 waves * TQ
constexpr int NT  = 256;  // targets per tile
constexpr int KC  = 16;   // d-depth per staged chunk
constexpr int CH  = 16;   // target chunks (grid.x of kernel B)
constexpr int BLK = 512;  // threads in kernel B

// rank (ad,ai) above (bd,bi): larger key first, tie -> smaller index
__device__ __forceinline__ bool pair_gt(float ad, int ai, float bd, int bi) {
  return (ad > bd) || (ad == bd && ai < bi);
}

// Branchless sorted insert into a descending top-5 (caller guarantees the
// candidate ranks above slot 4). All slot reads happen before overwrite.
__device__ __forceinline__ void top5_insert(float d2, int idx,
    float& t0d, float& t1d, float& t2d, float& t3d, float& t4d,
    int&   t0i, int&   t1i, int&   t2i, int&   t3i, int&   t4i) {
  const bool b3 = pair_gt(d2, idx, t3d, t3i);
  const bool b2 = pair_gt(d2, idx, t2d, t2i);
  const bool b1 = pair_gt(d2, idx, t1d, t1i);
  const bool b0 = pair_gt(d2, idx, t0d, t0i);
  t4d = b3 ? t3d : d2;               t4i = b3 ? t3i : idx;
  t3d = b3 ? (b2 ? t2d : d2) : t3d;  t3i = b3 ? (b2 ? t2i : idx) : t3i;
  t2d = b2 ? (b1 ? t1d : d2) : t2d;  t2i = b2 ? (b1 ? t1i : idx) : t2i;
  t1d = b1 ? (b0 ? t0d : d2) : t1d;  t1i = b1 ? (b0 ? t0i : idx) : t1i;
  t0d = b0 ? d2 : t0d;               t0i = b0 ? idx : t0i;
}

// ---------------- Kernel A: per-target squared norm (padded to Npad) ----------------
__launch_bounds__(256)
__global__ void sqnorm_kernel(const float* __restrict__ tg,
                              float* __restrict__ t2, int N, int Npad) {
  const int tid  = threadIdx.x;
  const int lane = tid & 63;
  const int wv   = tid >> 6;
  const int row  = blockIdx.x * 16 + wv * 4 + (lane >> 4);
  const int f4   = lane & 15;
  if (row >= Npad) return;
  float s = 0.0f;
  if (row < N) {
    const float4 v = reinterpret_cast<const float4*>(tg)[(size_t)row * 16 + f4];
    s = v.x*v.x + v.y*v.y + v.z*v.z + v.w*v.w;
    s += __shfl_xor(s, 1);
    s += __shfl_xor(s, 2);
    s += __shfl_xor(s, 4);
    s += __shfl_xor(s, 8);
  }
  if (f4 == 0) t2[row] = s;
}

// ---------------- Kernel B: distances + per-(query,chunk) top-5 ----------------
__launch_bounds__(BLK)
__global__ void knn_partial_kernel(const float* __restrict__ x,
                                   const float* __restrict__ tg,
                                   const float* __restrict__ t2w,
                                   float* __restrict__ pd,
                                   int*   __restrict__ pi,
                                   int N) {
  __shared__ float tbuf[2][KC][NT];  // 32 KiB, d-major target tile, double-buffered

  const int tid  = threadIdx.x;
  const int lane = tid & 63;
  const int w    = __builtin_amdgcn_readfirstlane(tid >> 6);  // wave id, uniform
  const int ci   = blockIdx.x;                                // target chunk
  const int q0   = blockIdx.y * QB + w * TQ;                  // wave's first query
  const float* xq = x + (size_t)q0 * DD;                      // wave-uniform base

  // per-thread top-5 per query (descending), key = t2 - 2*dot
  float td0[TQ], td1[TQ], td2[TQ], td3[TQ], td4[TQ];
  int   ti0[TQ], ti1[TQ], ti2[TQ], ti3[TQ], ti4[TQ];
  #pragma unroll
  for (int qi = 0; qi < TQ; ++qi) {
    td0[qi]=td1[qi]=td2[qi]=td3[qi]=td4[qi] = -1e30f;
    ti0[qi]=ti1[qi]=ti2[qi]=ti3[qi]=ti4[qi] = 0;
  }

  float acc[TQ][4];

  const int total_tiles = (N + NT - 1) / NT;
  const int mytiles = (ci < total_tiles) ? ((total_tiles - 1 - ci) / CH + 1) : 0;
  const int C = mytiles * 4;  // chunk iterations

  // staging registers (issue-early / write-late split)
  float4 sva = make_float4(0,0,0,0), svb = make_float4(0,0,0,0);
  const int n0  = tid & 255;          // this thread's target row in tile
  const int j40 = tid >> 8;           // float4 slot 0..1
  const int j41 = j40 + 2;            // float4 slot 2..3
  const float4* tgv = reinterpret_cast<const float4*>(tg);

  // ---- prologue: stage chunk 0 ----
  if (C > 0) {
    const long r0 = (long)ci * NT + n0;
    if (r0 < N) {
      sva = tgv[r0 * 16 + j40];
      svb = tgv[r0 * 16 + j41];
    }
    tbuf[0][j40*4+0][n0] = sva.x;  tbuf[0][j40*4+1][n0] = sva.y;
    tbuf[0][j40*4+2][n0] = sva.z;  tbuf[0][j40*4+3][n0] = sva.w;
    tbuf[0][j41*4+0][n0] = svb.x;  tbuf[0][j41*4+1][n0] = svb.y;
    tbuf[0][j41*4+2][n0] = svb.z;  tbuf[0][j41*4+3][n0] = svb.w;
  }
  __syncthreads();

  for (int c = 0; c < C; ++c) {
    const int b       = c & 1;
    const int kc      = c & 3;
    const int tileidx = ci + (c >> 2) * CH;
    const bool more   = (c + 1 < C);

    // 1) issue global loads for chunk c+1 (latency hides under compute)
    if (more) {
      const int gc2   = c + 1;
      const int kc2   = gc2 & 3;
      const int tile2 = ci + (gc2 >> 2) * CH;
      const long r0n  = (long)tile2 * NT + n0;
      sva = make_float4(0,0,0,0);
      svb = make_float4(0,0,0,0);
      if (r0n < N) {
        sva = tgv[r0n * 16 + kc2 * 4 + j40];
        svb = tgv[r0n * 16 + kc2 * 4 + j41];
      }
    }

    // 2) compute chunk c
    if (kc == 0) {
      #pragma unroll
      for (int qi = 0; qi < TQ; ++qi) {
        acc[qi][0]=0.f; acc[qi][1]=0.f; acc[qi][2]=0.f; acc[qi][3]=0.f;
      }
    }
    #pragma unroll
    for (int h = 0; h < 2; ++h) {
      // 8 d-values per query for this half-chunk, as two float4 loads each
      // (wave-uniform address -> one cache line per load).
      const int dbase = kc * KC + h * 8;
      float qs[TQ][8];
      #pragma unroll
      for (int qi = 0; qi < TQ; ++qi) {
        const float4 qa = *reinterpret_cast<const float4*>(xq + qi * DD + dbase);
        const float4 qb = *reinterpret_cast<const float4*>(xq + qi * DD + dbase + 4);
        qs[qi][0]=qa.x; qs[qi][1]=qa.y; qs[qi][2]=qa.z; qs[qi][3]=qa.w;
        qs[qi][4]=qb.x; qs[qi][5]=qb.y; qs[qi][6]=qb.z; qs[qi][7]=qb.w;
      }
      #pragma unroll
      for (int dd = 0; dd < 8; ++dd) {
        const float4 tv = *reinterpret_cast<const float4*>(&tbuf[b][h*8+dd][lane*4]);
        #pragma unroll
        for (int qi = 0; qi < TQ; ++qi) {
          acc[qi][0] = fmaf(qs[qi][dd], tv.x, acc[qi][0]);
          acc[qi][1] = fmaf(qs[qi][dd], tv.y, acc[qi][1]);
          acc[qi][2] = fmaf(qs[qi][dd], tv.z, acc[qi][2]);
          acc[qi][3] = fmaf(qs[qi][dd], tv.w, acc[qi][3]);
        }
      }
    }

    // 3) tile epilogue: key = t2 - 2*dot, update top-5
    if (kc == 3) {
      const int nb = tileidx * NT + lane * 4;
      const float4 t2v = *reinterpret_cast<const float4*>(t2w + nb);  // t2w padded
      const float t2a[4] = { t2v.x, t2v.y, t2v.z, t2v.w };
      #pragma unroll
      for (int qi = 0; qi < TQ; ++qi) {
        #pragma unroll
        for (int j = 0; j < 4; ++j) {
          const float r2  = fmaf(-2.0f, acc[qi][j], t2a[j]);
          const int   idx = nb + j;
          if (idx < N && pair_gt(r2, idx, td4[qi], ti4[qi]))
            top5_insert(r2, idx,
                        td0[qi], td1[qi], td2[qi], td3[qi], td4[qi],
                        ti0[qi], ti1[qi], ti2[qi], ti3[qi], ti4[qi]);
        }
      }
    }

    // 4) write staged chunk c+1 into the other buffer
    if (more) {
      const int bo = (c + 1) & 1;
      tbuf[bo][j40*4+0][n0] = sva.x;  tbuf[bo][j40*4+1][n0] = sva.y;
      tbuf[bo][j40*4+2][n0] = sva.z;  tbuf[bo][j40*4+3][n0] = sva.w;
      tbuf[bo][j41*4+0][n0] = svb.x;  tbuf[bo][j41*4+1][n0] = svb.y;
      tbuf[bo][j41*4+2][n0] = svb.z;  tbuf[bo][j41*4+3][n0] = svb.w;
    }
    __syncthreads();
  }

  // ---- cross-lane merge: wave top-5 per query, write partials ----
  #pragma unroll
  for (int qi = 0; qi < TQ; ++qi) {
    float rd[KNN]; int ri[KNN];
    #pragma unroll
    for (int r = 0; r < KNN; ++r) {
      float md = td0[qi]; int mi = ti0[qi];
      #pragma unroll
      for (int k = 1; k < 64; k <<= 1) {
        const float od = __shfl_xor(md, k);
        const int   oi = __shfl_xor(mi, k);
        if (pair_gt(od, oi, md, mi)) { md = od; mi = oi; }
      }
      rd[r] = md; ri[r] = mi;
      if (ti0[qi] == mi && td0[qi] == md) {  // consume winner (indices unique)
        td0[qi]=td1[qi]; ti0[qi]=ti1[qi];
        td1[qi]=td2[qi]; ti1[qi]=ti2[qi];
        td2[qi]=td3[qi]; ti2[qi]=ti3[qi];
        td3[qi]=td4[qi]; ti3[qi]=ti4[qi];
        td4[qi]=-1e30f;  ti4[qi]=0;
      }
    }
    if (lane == 0) {
      const int pbase = (q0 + qi) * (CH * KNN) + ci * KNN;
      #pragma unroll
      for (int r = 0; r < KNN; ++r) { pd[pbase + r] = rd[r]; pi[pbase + r] = ri[r]; }
    }
  }
}

// ---------------- Kernel C: merge partials, gather, mean ----------------
__launch_bounds__(64)
__global__ void merge_kernel(const float* __restrict__ tg,
                             const float* __restrict__ pd,
                             const int*   __restrict__ pi,
                             float* __restrict__ out, int chn) {
  const int q    = blockIdx.x;
  const int lane = threadIdx.x;   // 64 threads
  const int M    = chn * KNN;     // 80 candidates
  const int pb   = q * M;
  float c0d = -1e30f, c1d = -1e30f;
  int   c0i = 0,      c1i = 0;
  if (lane < M)      { c0d = pd[pb + lane];      c0i = pi[pb + lane]; }
  if (lane + 64 < M) { c1d = pd[pb + lane + 64]; c1i = pi[pb + lane + 64]; }
  if (pair_gt(c1d, c1i, c0d, c0i)) {
    const float tdm = c0d; const int tim = c0i;
    c0d = c1d; c0i = c1i; c1d = tdm; c1i = tim;
  }
  int sel[KNN];
  #pragma unroll
  for (int r = 0; r < KNN; ++r) {
    float md = c0d; int mi = c0i;
    #pragma unroll
    for (int k = 1; k < 64; k <<= 1) {
      const float od = __shfl_xor(md, k);
      const int   oi = __shfl_xor(mi, k);
      if (pair_gt(od, oi, md, mi)) { md = od; mi = oi; }
    }
    sel[r] = mi;
    if (c0i == mi && c0d == md) { c0d = c1d; c0i = c1i; c1d = -1e30f; c1i = 0; }
  }
  float s = 0.0f;
  #pragma unroll
  for (int r = 0; r < KNN; ++r) s += tg[(size_t)sel[r] * DD + lane];
  out[(size_t)q * DD + lane] = s / 5.0f;
}

// ---------------- Fallback (only if workspace too small) ----------------
__launch_bounds__(256)
__global__ void knn_fallback(const float* __restrict__ x,
                             const float* __restrict__ tg,
                             float* __restrict__ out, int N) {
  const int q   = blockIdx.x;
  const int tid = threadIdx.x;
  __shared__ float qsh[DD];
  __shared__ float smd[KNN][256];
  __shared__ int   smi[KNN][256];
  if (tid < DD) qsh[tid] = x[(size_t)q * DD + tid];
  __syncthreads();
  float qv[DD];
  #pragma unroll
  for (int d = 0; d < DD; ++d) qv[d] = qsh[d];
  float x2 = 0.0f;
  #pragma unroll
  for (int d = 0; d < DD; ++d) x2 = fmaf(qv[d], qv[d], x2);
  float a0=-1e30f,a1=-1e30f,a2=-1e30f,a3=-1e30f,a4=-1e30f;
  int   i0=0,i1=0,i2=0,i3=0,i4=0;
  for (int n = tid; n < N; n += 256) {
    const float4* tr = reinterpret_cast<const float4*>(tg + (size_t)n * DD);
    float dot = 0.0f, tt = 0.0f;
    #pragma unroll
    for (int k = 0; k < 16; ++k) {
      const float4 tv = tr[k];
      dot = fmaf(qv[4*k+0], tv.x, dot); tt = fmaf(tv.x, tv.x, tt);
      dot = fmaf(qv[4*k+1], tv.y, dot); tt = fmaf(tv.y, tv.y, tt);
      dot = fmaf(qv[4*k+2], tv.z, dot); tt = fmaf(tv.z, tv.z, tt);
      dot = fmaf(qv[4*k+3], tv.w, dot); tt = fmaf(tv.w, tv.w, tt);
    }
    const float d2 = fmaf(-2.0f, dot, x2 + tt);
    if (pair_gt(d2, n, a4, i4))
      top5_insert(d2, n, a0,a1,a2,a3,a4, i0,i1,i2,i3,i4);
  }
  smd[0][tid]=a0; smi[0][tid]=i0;  smd[1][tid]=a1; smi[1][tid]=i1;
  smd[2][tid]=a2; smi[2][tid]=i2;  smd[3][tid]=a3; smi[3][tid]=i3;
  smd[4][tid]=a4; smi[4][tid]=i4;
  __syncthreads();
  if (tid < 64) {
    a0=a1=a2=a3=a4=-1e30f; i0=i1=i2=i3=i4=0;
    for (int src = tid; src < 256; src += 64) {
      #pragma unroll
      for (int r = 0; r < KNN; ++r) {
        const float dd2 = smd[r][src]; const int ii = smi[r][src];
        if (pair_gt(dd2, ii, a4, i4))
          top5_insert(dd2, ii, a0,a1,a2,a3,a4, i0,i1,i2,i3,i4);
      }
    }
    int sel[KNN];
    #pragma unroll
    for (int r = 0; r < KNN; ++r) {
      float md = a0; int mi = i0;
      #pragma unroll
      for (int k = 1; k < 64; k <<= 1) {
        const float od = __shfl_xor(md, k);
        const int   oi = __shfl_xor(mi, k);
        if (pair_gt(od, oi, md, mi)) { md = od; mi = oi; }
      }
      sel[r] = mi;
      if (i0 == mi && a0 == md) {
        a0=a1; i0=i1; a1=a2; i1=i2; a2=a3; i2=i3; a3=a4; i3=i4; a4=-1e30f; i4=0;
      }
    }
    float s = 0.0f;
    #pragma unroll
    for (int r = 0; r < KNN; ++r) s += tg[(size_t)sel[r] * DD + tid];
    out[(size_t)q * DD + tid] = s / 5.0f;
  }
}

extern "C" void kernel_launch(void* const* d_in, const int* in_sizes, int n_in,
                              void* d_out, int out_size, void* d_ws, size_t ws_size,
                              hipStream_t stream) {
  const float* x  = (const float*)d_in[0];
  const float* tg = (const float*)d_in[1];
  float* out = (float*)d_out;
  const int B = in_sizes[0] / DD;   // 2048
  const int N = in_sizes[1] / DD;   // 50000

  const int    Npad     = (N + NT - 1) & ~(NT - 1);   // pad to tile multiple (50176)
  const size_t t2_elems = (size_t)Npad;
  const size_t npart    = (size_t)B * CH * KNN;
  const size_t need     = (t2_elems + 2 * npart) * sizeof(float);

  if (ws_size >= need && (B % QB) == 0) {
    float* t2 = (float*)d_ws;
    float* pd = t2 + t2_elems;
    int*   pi = (int*)(pd + npart);
    sqnorm_kernel<<<dim3(Npad / 16), dim3(256), 0, stream>>>(tg, t2, N, Npad);
    knn_partial_kernel<<<dim3(CH, B / QB), dim3(BLK), 0, stream>>>(x, tg, t2, pd, pi, N);
    merge_kernel<<<dim3(B), dim3(64), 0, stream>>>(tg, pd, pi, out, CH);
  } else {
    knn_fallback<<<dim3(B), dim3(256), 0, stream>>>(x, tg, out, N);
  }
}

// Round 4
// 425.813 us; speedup vs baseline: 2.6675x; 1.7419x over previous
//
#include <hip/hip_runtime.h>

// KNN (k=5, LARGEST distances per faithful-to-source quirk) + gather-mean.
// x: [B=2048, 64] f32, target: [N=50000, 64] f32, out: [B, 64] f32.
//
// Round-4: distance GEMM on MFMA via f16 hi/lo split (error ~4e-6, fp32-grade):
//   x = hi + lo*2^-12 (lo stored pre-scaled by 2^12 to stay in f16 normal range)
//   dot = hh + 2^-12*(hl + lh) + 2^-24*ll   -> 8 mfma_f32_16x16x32_f16 per tile
// Ranking key r2 = ||t||^2 - 2*dot (order-equivalent to d2 per query).
// Padded target rows get t2 = -1e30 -> never selected (no per-candidate N-check).

typedef _Float16 f16x8 __attribute__((ext_vector_type(8)));
typedef float    f32x4 __attribute__((ext_vector_type(4)));

constexpr int KNN = 5;
constexpr int DD  = 64;    // feature dim
constexpr int NTT = 16;    // targets per MFMA tile
constexpr int GT  = 2;     // tiles staged per phase
constexpr int CH2 = 32;    // target chunks (MFMA path)
constexpr int QBB = 64;    // queries per block (MFMA path, 4 waves x 16)

// tier-2 (VALU) constants — round-3 kernel kept as fallback
constexpr int TQ  = 4;
constexpr int QB  = 32;
constexpr int NT  = 256;
constexpr int KC  = 16;
constexpr int CH  = 16;
constexpr int BLK = 512;

__device__ __forceinline__ bool pair_gt(float ad, int ai, float bd, int bi) {
  return (ad > bd) || (ad == bd && ai < bi);
}

__device__ __forceinline__ void top5_insert(float d2, int idx,
    float& t0d, float& t1d, float& t2d, float& t3d, float& t4d,
    int&   t0i, int&   t1i, int&   t2i, int&   t3i, int&   t4i) {
  const bool b3 = pair_gt(d2, idx, t3d, t3i);
  const bool b2 = pair_gt(d2, idx, t2d, t2i);
  const bool b1 = pair_gt(d2, idx, t1d, t1i);
  const bool b0 = pair_gt(d2, idx, t0d, t0i);
  t4d = b3 ? t3d : d2;               t4i = b3 ? t3i : idx;
  t3d = b3 ? (b2 ? t2d : d2) : t3d;  t3i = b3 ? (b2 ? t2i : idx) : t3i;
  t2d = b2 ? (b1 ? t1d : d2) : t2d;  t2i = b2 ? (b1 ? t1i : idx) : t2i;
  t1d = b1 ? (b0 ? t0d : d2) : t1d;  t1i = b1 ? (b0 ? t0i : idx) : t1i;
  t0d = b0 ? d2 : t0d;               t0i = b0 ? idx : t0i;
}

__device__ __forceinline__ void gload16(const void* g, void* l) {
  __builtin_amdgcn_global_load_lds(
      (const __attribute__((address_space(1))) unsigned int*)g,
      (__attribute__((address_space(3))) unsigned int*)l, 16, 0, 0);
}

// ---------------- Kernel A: per-target squared norm; pad rows = -1e30 ----------------
__launch_bounds__(256)
__global__ void sqnorm_kernel(const float* __restrict__ tg,
                              float* __restrict__ t2, int N, int Npad) {
  const int tid  = threadIdx.x;
  const int lane = tid & 63;
  const int wv   = tid >> 6;
  const int row  = blockIdx.x * 16 + wv * 4 + (lane >> 4);
  const int f4   = lane & 15;
  if (row >= Npad) return;
  float s = -1e30f;
  if (row < N) {
    const float4 v = reinterpret_cast<const float4*>(tg)[(size_t)row * 16 + f4];
    s = v.x*v.x + v.y*v.y + v.z*v.z + v.w*v.w;
    s += __shfl_xor(s, 1);
    s += __shfl_xor(s, 2);
    s += __shfl_xor(s, 4);
    s += __shfl_xor(s, 8);
  }
  if (f4 == 0) t2[row] = s;
}

// ------------- Kernel A2: convert targets to f16 hi/lo tile image -------------
// Layout per tile (4096 B): [term(2)][kb(8)][col(16)][i(8)] f16;  k = kb*8+i.
__launch_bounds__(256)
__global__ void cvt_kernel(const float* __restrict__ tg,
                           unsigned short* __restrict__ tcvt,
                           int N, int TT) {
  const int tid  = threadIdx.x;
  const int lane = tid & 63;
  const int w    = __builtin_amdgcn_readfirstlane(tid >> 6);
  const int t    = blockIdx.x * 4 + w;          // tile index
  if (t >= TT) return;
  const int col   = lane & 15;
  const int khalf = lane >> 4;                  // 0..3
  const int row   = t * NTT + col;              // global target row
  #pragma unroll
  for (int j = 0; j < 2; ++j) {
    const int kb = khalf * 2 + j;               // 0..7
    float v[8];
    if (row < N) {
      const float4 a = *reinterpret_cast<const float4*>(tg + (size_t)row * DD + kb * 8);
      const float4 b = *reinterpret_cast<const float4*>(tg + (size_t)row * DD + kb * 8 + 4);
      v[0]=a.x; v[1]=a.y; v[2]=a.z; v[3]=a.w;
      v[4]=b.x; v[5]=b.y; v[6]=b.z; v[7]=b.w;
    } else {
      #pragma unroll
      for (int i = 0; i < 8; ++i) v[i] = 0.0f;
    }
    f16x8 hv, lv;
    #pragma unroll
    for (int i = 0; i < 8; ++i) {
      const _Float16 h = (_Float16)v[i];
      hv[i] = h;
      lv[i] = (_Float16)((v[i] - (float)h) * 4096.0f);
    }
    const size_t off = (size_t)t * 2048 + kb * 128 + col * 8;  // ushort units
    *reinterpret_cast<f16x8*>(tcvt + off)        = hv;
    *reinterpret_cast<f16x8*>(tcvt + off + 1024) = lv;
  }
}

// ---------------- Kernel B (MFMA): distances + per-(query,chunk) top-5 ----------------
__launch_bounds__(256)
__global__ void knn_mfma_kernel(const float* __restrict__ x,
                                const unsigned short* __restrict__ tcvt,
                                const float* __restrict__ t2w,
                                float* __restrict__ pd,
                                int*   __restrict__ pi,
                                int TT) {
  __shared__ unsigned short sbuf[2][GT][2048];  // 16 KiB: 2-phase x GT tiles x 4KB

  const int tid  = threadIdx.x;
  const int lane = tid & 63;
  const int w    = __builtin_amdgcn_readfirstlane(tid >> 6);
  const int ci   = blockIdx.x;                  // target chunk
  const int q0w  = blockIdx.y * QBB + w * 16;   // wave's first query
  const int col  = lane & 15;                   // B col / A row for input frags
  const int kb   = lane >> 4;                   // 0..3

  // ---- A fragments: 16 queries x 64 d, f16 hi/lo, held in regs all kernel ----
  f16x8 ah[2], al[2];
  #pragma unroll
  for (int c = 0; c < 2; ++c) {
    const float* xp = x + (size_t)(q0w + col) * DD + c * 32 + kb * 8;
    const float4 a = *reinterpret_cast<const float4*>(xp);
    const float4 b = *reinterpret_cast<const float4*>(xp + 4);
    float v[8] = {a.x, a.y, a.z, a.w, b.x, b.y, b.z, b.w};
    #pragma unroll
    for (int i = 0; i < 8; ++i) {
      const _Float16 h = (_Float16)v[i];
      ah[c][i] = h;
      al[c][i] = (_Float16)((v[i] - (float)h) * 4096.0f);
    }
  }

  // per-lane top-5 per C-reg slot (4 queries/lane)
  float td0[4], td1[4], td2[4], td3[4], td4[4];
  int   ti0[4], ti1[4], ti2[4], ti3[4], ti4[4];
  #pragma unroll
  for (int r = 0; r < 4; ++r) {
    td0[r]=td1[r]=td2[r]=td3[r]=td4[r] = -1e30f;
    ti0[r]=ti1[r]=ti2[r]=ti3[r]=ti4[r] = 0;
  }

  const int mytiles = (ci < TT) ? ((TT - 1 - ci) / CH2 + 1) : 0;
  const int NP = (mytiles + GT - 1) / GT;

  // ---- stage phase 0 ----
  #pragma unroll
  for (int g = 0; g < GT; ++g) {
    if (g < mytiles) {
      const size_t ti = (size_t)(ci + g * CH2);
      gload16(tcvt + ti * 2048 + tid * 8, &sbuf[0][g][tid * 8]);
    }
  }
  __syncthreads();

  const int lbase = kb * 256 + col * 16;        // byte offset of this lane's frag

  for (int p = 0; p < NP; ++p) {
    const int bp = p & 1;
    // 1) stage phase p+1
    if (p + 1 < NP) {
      #pragma unroll
      for (int g = 0; g < GT; ++g) {
        const int j = (p + 1) * GT + g;
        if (j < mytiles) {
          const size_t ti = (size_t)(ci + j * CH2);
          gload16(tcvt + ti * 2048 + tid * 8, &sbuf[bp ^ 1][g][tid * 8]);
        }
      }
    }
    // 2) compute phase p
    #pragma unroll
    for (int g = 0; g < GT; ++g) {
      const int j = p * GT + g;
      if (j < mytiles) {
        const int ti = ci + j * CH2;
        const char* tb = (const char*)&sbuf[bp][g][0];
        const f16x8 bh0 = *reinterpret_cast<const f16x8*>(tb + lbase);
        const f16x8 bh1 = *reinterpret_cast<const f16x8*>(tb + lbase + 1024);
        const f16x8 bl0 = *reinterpret_cast<const f16x8*>(tb + lbase + 2048);
        const f16x8 bl1 = *reinterpret_cast<const f16x8*>(tb + lbase + 3072);
        f32x4 acc_hh = {0.f, 0.f, 0.f, 0.f};
        f32x4 acc_m  = {0.f, 0.f, 0.f, 0.f};
        f32x4 acc_ll = {0.f, 0.f, 0.f, 0.f};
        acc_hh = __builtin_amdgcn_mfma_f32_16x16x32_f16(ah[0], bh0, acc_hh, 0, 0, 0);
        acc_hh = __builtin_amdgcn_mfma_f32_16x16x32_f16(ah[1], bh1, acc_hh, 0, 0, 0);
        acc_m  = __builtin_amdgcn_mfma_f32_16x16x32_f16(ah[0], bl0, acc_m, 0, 0, 0);
        acc_m  = __builtin_amdgcn_mfma_f32_16x16x32_f16(ah[1], bl1, acc_m, 0, 0, 0);
        acc_m  = __builtin_amdgcn_mfma_f32_16x16x32_f16(al[0], bh0, acc_m, 0, 0, 0);
        acc_m  = __builtin_amdgcn_mfma_f32_16x16x32_f16(al[1], bh1, acc_m, 0, 0, 0);
        acc_ll = __builtin_amdgcn_mfma_f32_16x16x32_f16(al[0], bl0, acc_ll, 0, 0, 0);
        acc_ll = __builtin_amdgcn_mfma_f32_16x16x32_f16(al[1], bl1, acc_ll, 0, 0, 0);
        // epilogue: r2 = t2 - 2*dot; idx = ti*16 + col (same for all 4 regs)
        const int   idx = ti * NTT + col;
        const float t2c = t2w[idx];
        #pragma unroll
        for (int r = 0; r < 4; ++r) {
          float dot = fmaf(acc_m[r], 0x1p-12f, acc_hh[r]);
          dot = fmaf(acc_ll[r], 0x1p-24f, dot);
          const float r2 = fmaf(-2.0f, dot, t2c);
          if (pair_gt(r2, idx, td4[r], ti4[r]))
            top5_insert(r2, idx,
                        td0[r], td1[r], td2[r], td3[r], td4[r],
                        ti0[r], ti1[r], ti2[r], ti3[r], ti4[r]);
        }
      }
    }
    __syncthreads();
  }

  // ---- merge within each 16-lane group (one group per 4 queries) ----
  // query of (lane,reg r): q0w + (lane>>4)*4 + r; its candidates live in the
  // 16 lanes sharing lane>>4 (shfl_xor masks 1,2,4,8 stay in-group).
  #pragma unroll
  for (int r = 0; r < 4; ++r) {
    float rd[KNN]; int ri[KNN];
    #pragma unroll
    for (int rr = 0; rr < KNN; ++rr) {
      float md = td0[r]; int mi = ti0[r];
      #pragma unroll
      for (int k = 1; k < 16; k <<= 1) {
        const float od = __shfl_xor(md, k);
        const int   oi = __shfl_xor(mi, k);
        if (pair_gt(od, oi, md, mi)) { md = od; mi = oi; }
      }
      rd[rr] = md; ri[rr] = mi;
      if (ti0[r] == mi && td0[r] == md) {
        td0[r]=td1[r]; ti0[r]=ti1[r];
        td1[r]=td2[r]; ti1[r]=ti2[r];
        td2[r]=td3[r]; ti2[r]=ti3[r];
        td3[r]=td4[r]; ti3[r]=ti4[r];
        td4[r]=-1e30f; ti4[r]=0;
      }
    }
    if (col == 0) {
      const int q = q0w + (lane >> 4) * 4 + r;
      const int pbase = q * (CH2 * KNN) + ci * KNN;
      #pragma unroll
      for (int rr = 0; rr < KNN; ++rr) { pd[pbase + rr] = rd[rr]; pi[pbase + rr] = ri[rr]; }
    }
  }
}

// ---------------- Kernel C: merge partials (up to 192 cands), gather, mean ----------------
__launch_bounds__(64)
__global__ void merge_kernel(const float* __restrict__ tg,
                             const float* __restrict__ pd,
                             const int*   __restrict__ pi,
                             float* __restrict__ out, int chn) {
  const int q    = blockIdx.x;
  const int lane = threadIdx.x;   // 64 threads
  const int M    = chn * KNN;     // 80 or 160 candidates
  const int pb   = q * M;
  float cd[3]; int cix[3];
  #pragma unroll
  for (int s = 0; s < 3; ++s) {
    const int i = lane + s * 64;
    const bool v = i < M;
    cd[s]  = v ? pd[pb + i] : -1e30f;
    cix[s] = v ? pi[pb + i] : 0;
  }
  int sel[KNN];
  #pragma unroll
  for (int r = 0; r < KNN; ++r) {
    float md = cd[0]; int mi = cix[0];
    if (pair_gt(cd[1], cix[1], md, mi)) { md = cd[1]; mi = cix[1]; }
    if (pair_gt(cd[2], cix[2], md, mi)) { md = cd[2]; mi = cix[2]; }
    #pragma unroll
    for (int k = 1; k < 64; k <<= 1) {
      const float od = __shfl_xor(md, k);
      const int   oi = __shfl_xor(mi, k);
      if (pair_gt(od, oi, md, mi)) { md = od; mi = oi; }
    }
    sel[r] = mi;
    #pragma unroll
    for (int s = 0; s < 3; ++s)
      if (cix[s] == mi && cd[s] == md) cd[s] = -1e30f;
  }
  float s = 0.0f;
  #pragma unroll
  for (int r = 0; r < KNN; ++r) s += tg[(size_t)sel[r] * DD + lane];
  out[(size_t)q * DD + lane] = s / 5.0f;
}

// ---------------- Tier-2 (round-3 VALU kernel, fallback if ws too small) ----------------
__launch_bounds__(BLK)
__global__ void knn_partial_kernel(const float* __restrict__ x,
                                   const float* __restrict__ tg,
                                   const float* __restrict__ t2w,
                                   float* __restrict__ pd,
                                   int*   __restrict__ pi,
                                   int N) {
  __shared__ float tbuf[2][KC][NT];

  const int tid  = threadIdx.x;
  const int lane = tid & 63;
  const int w    = __builtin_amdgcn_readfirstlane(tid >> 6);
  const int ci   = blockIdx.x;
  const int q0   = blockIdx.y * QB + w * TQ;
  const float* xq = x + (size_t)q0 * DD;

  float td0[TQ], td1[TQ], td2[TQ], td3[TQ], td4[TQ];
  int   ti0[TQ], ti1[TQ], ti2[TQ], ti3[TQ], ti4[TQ];
  #pragma unroll
  for (int qi = 0; qi < TQ; ++qi) {
    td0[qi]=td1[qi]=td2[qi]=td3[qi]=td4[qi] = -1e30f;
    ti0[qi]=ti1[qi]=ti2[qi]=ti3[qi]=ti4[qi] = 0;
  }

  float acc[TQ][4];
  const int total_tiles = (N + NT - 1) / NT;
  const int mytiles = (ci < total_tiles) ? ((total_tiles - 1 - ci) / CH + 1) : 0;
  const int C = mytiles * 4;

  float4 sva = make_float4(0,0,0,0), svb = make_float4(0,0,0,0);
  const int n0  = tid & 255;
  const int j40 = tid >> 8;
  const int j41 = j40 + 2;
  const float4* tgv = reinterpret_cast<const float4*>(tg);

  if (C > 0) {
    const long r0 = (long)ci * NT + n0;
    if (r0 < N) { sva = tgv[r0 * 16 + j40]; svb = tgv[r0 * 16 + j41]; }
    tbuf[0][j40*4+0][n0] = sva.x;  tbuf[0][j40*4+1][n0] = sva.y;
    tbuf[0][j40*4+2][n0] = sva.z;  tbuf[0][j40*4+3][n0] = sva.w;
    tbuf[0][j41*4+0][n0] = svb.x;  tbuf[0][j41*4+1][n0] = svb.y;
    tbuf[0][j41*4+2][n0] = svb.z;  tbuf[0][j41*4+3][n0] = svb.w;
  }
  __syncthreads();

  for (int c = 0; c < C; ++c) {
    const int b       = c & 1;
    const int kc      = c & 3;
    const int tileidx = ci + (c >> 2) * CH;
    const bool more   = (c + 1 < C);

    if (more) {
      const int gc2   = c + 1;
      const int kc2   = gc2 & 3;
      const int tile2 = ci + (gc2 >> 2) * CH;
      const long r0n  = (long)tile2 * NT + n0;
      sva = make_float4(0,0,0,0);
      svb = make_float4(0,0,0,0);
      if (r0n < N) {
        sva = tgv[r0n * 16 + kc2 * 4 + j40];
        svb = tgv[r0n * 16 + kc2 * 4 + j41];
      }
    }

    if (kc == 0) {
      #pragma unroll
      for (int qi = 0; qi < TQ; ++qi) {
        acc[qi][0]=0.f; acc[qi][1]=0.f; acc[qi][2]=0.f; acc[qi][3]=0.f;
      }
    }
    #pragma unroll
    for (int h = 0; h < 2; ++h) {
      const int dbase = kc * KC + h * 8;
      float qs[TQ][8];
      #pragma unroll
      for (int qi = 0; qi < TQ; ++qi) {
        const float4 qa = *reinterpret_cast<const float4*>(xq + qi * DD + dbase);
        const float4 qb = *reinterpret_cast<const float4*>(xq + qi * DD + dbase + 4);
        qs[qi][0]=qa.x; qs[qi][1]=qa.y; qs[qi][2]=qa.z; qs[qi][3]=qa.w;
        qs[qi][4]=qb.x; qs[qi][5]=qb.y; qs[qi][6]=qb.z; qs[qi][7]=qb.w;
      }
      #pragma unroll
      for (int dd = 0; dd < 8; ++dd) {
        const float4 tv = *reinterpret_cast<const float4*>(&tbuf[b][h*8+dd][lane*4]);
        #pragma unroll
        for (int qi = 0; qi < TQ; ++qi) {
          acc[qi][0] = fmaf(qs[qi][dd], tv.x, acc[qi][0]);
          acc[qi][1] = fmaf(qs[qi][dd], tv.y, acc[qi][1]);
          acc[qi][2] = fmaf(qs[qi][dd], tv.z, acc[qi][2]);
          acc[qi][3] = fmaf(qs[qi][dd], tv.w, acc[qi][3]);
        }
      }
    }

    if (kc == 3) {
      const int nb = tileidx * NT + lane * 4;
      const float4 t2v = *reinterpret_cast<const float4*>(t2w + nb);
      const float t2a[4] = { t2v.x, t2v.y, t2v.z, t2v.w };
      #pragma unroll
      for (int qi = 0; qi < TQ; ++qi) {
        #pragma unroll
        for (int j = 0; j < 4; ++j) {
          const float r2  = fmaf(-2.0f, acc[qi][j], t2a[j]);
          const int   idx = nb + j;
          if (idx < N && pair_gt(r2, idx, td4[qi], ti4[qi]))
            top5_insert(r2, idx,
                        td0[qi], td1[qi], td2[qi], td3[qi], td4[qi],
                        ti0[qi], ti1[qi], ti2[qi], ti3[qi], ti4[qi]);
        }
      }
    }

    if (more) {
      const int bo = (c + 1) & 1;
      tbuf[bo][j40*4+0][n0] = sva.x;  tbuf[bo][j40*4+1][n0] = sva.y;
      tbuf[bo][j40*4+2][n0] = sva.z;  tbuf[bo][j40*4+3][n0] = sva.w;
      tbuf[bo][j41*4+0][n0] = svb.x;  tbuf[bo][j41*4+1][n0] = svb.y;
      tbuf[bo][j41*4+2][n0] = svb.z;  tbuf[bo][j41*4+3][n0] = svb.w;
    }
    __syncthreads();
  }

  #pragma unroll
  for (int qi = 0; qi < TQ; ++qi) {
    float rd[KNN]; int ri[KNN];
    #pragma unroll
    for (int r = 0; r < KNN; ++r) {
      float md = td0[qi]; int mi = ti0[qi];
      #pragma unroll
      for (int k = 1; k < 64; k <<= 1) {
        const float od = __shfl_xor(md, k);
        const int   oi = __shfl_xor(mi, k);
        if (pair_gt(od, oi, md, mi)) { md = od; mi = oi; }
      }
      rd[r] = md; ri[r] = mi;
      if (ti0[qi] == mi && td0[qi] == md) {
        td0[qi]=td1[qi]; ti0[qi]=ti1[qi];
        td1[qi]=td2[qi]; ti1[qi]=ti2[qi];
        td2[qi]=td3[qi]; ti2[qi]=ti3[qi];
        td3[qi]=td4[qi]; ti3[qi]=ti4[qi];
        td4[qi]=-1e30f;  ti4[qi]=0;
      }
    }
    if (lane == 0) {
      const int pbase = (q0 + qi) * (CH * KNN) + ci * KNN;
      #pragma unroll
      for (int r = 0; r < KNN; ++r) { pd[pbase + r] = rd[r]; pi[pbase + r] = ri[r]; }
    }
  }
}

// ---------------- Tier-3 fallback ----------------
__launch_bounds__(256)
__global__ void knn_fallback(const float* __restrict__ x,
                             const float* __restrict__ tg,
                             float* __restrict__ out, int N) {
  const int q   = blockIdx.x;
  const int tid = threadIdx.x;
  __shared__ float qsh[DD];
  __shared__ float smd[KNN][256];
  __shared__ int   smi[KNN][256];
  if (tid < DD) qsh[tid] = x[(size_t)q * DD + tid];
  __syncthreads();
  float qv[DD];
  #pragma unroll
  for (int d = 0; d < DD; ++d) qv[d] = qsh[d];
  float x2 = 0.0f;
  #pragma unroll
  for (int d = 0; d < DD; ++d) x2 = fmaf(qv[d], qv[d], x2);
  float a0=-1e30f,a1=-1e30f,a2=-1e30f,a3=-1e30f,a4=-1e30f;
  int   i0=0,i1=0,i2=0,i3=0,i4=0;
  for (int n = tid; n < N; n += 256) {
    const float4* tr = reinterpret_cast<const float4*>(tg + (size_t)n * DD);
    float dot = 0.0f, tt = 0.0f;
    #pragma unroll
    for (int k = 0; k < 16; ++k) {
      const float4 tv = tr[k];
      dot = fmaf(qv[4*k+0], tv.x, dot); tt = fmaf(tv.x, tv.x, tt);
      dot = fmaf(qv[4*k+1], tv.y, dot); tt = fmaf(tv.y, tv.y, tt);
      dot = fmaf(qv[4*k+2], tv.z, dot); tt = fmaf(tv.z, tv.z, tt);
      dot = fmaf(qv[4*k+3], tv.w, dot); tt = fmaf(tv.w, tv.w, tt);
    }
    const float d2 = fmaf(-2.0f, dot, x2 + tt);
    if (pair_gt(d2, n, a4, i4))
      top5_insert(d2, n, a0,a1,a2,a3,a4, i0,i1,i2,i3,i4);
  }
  smd[0][tid]=a0; smi[0][tid]=i0;  smd[1][tid]=a1; smi[1][tid]=i1;
  smd[2][tid]=a2; smi[2][tid]=i2;  smd[3][tid]=a3; smi[3][tid]=i3;
  smd[4][tid]=a4; smi[4][tid]=i4;
  __syncthreads();
  if (tid < 64) {
    a0=a1=a2=a3=a4=-1e30f; i0=i1=i2=i3=i4=0;
    for (int src = tid; src < 256; src += 64) {
      #pragma unroll
      for (int r = 0; r < KNN; ++r) {
        const float dd2 = smd[r][src]; const int ii = smi[r][src];
        if (pair_gt(dd2, ii, a4, i4))
          top5_insert(dd2, ii, a0,a1,a2,a3,a4, i0,i1,i2,i3,i4);
      }
    }
    int sel[KNN];
    #pragma unroll
    for (int r = 0; r < KNN; ++r) {
      float md = a0; int mi = i0;
      #pragma unroll
      for (int k = 1; k < 64; k <<= 1) {
        const float od = __shfl_xor(md, k);
        const int   oi = __shfl_xor(mi, k);
        if (pair_gt(od, oi, md, mi)) { md = od; mi = oi; }
      }
      sel[r] = mi;
      if (i0 == mi && a0 == md) {
        a0=a1; i0=i1; a1=a2; i1=i2; a2=a3; i2=i3; a3=a4; i3=i4; a4=-1e30f; i4=0;
      }
    }
    float s = 0.0f;
    #pragma unroll
    for (int r = 0; r < KNN; ++r) s += tg[(size_t)sel[r] * DD + tid];
    out[(size_t)q * DD + tid] = s / 5.0f;
  }
}

extern "C" void kernel_launch(void* const* d_in, const int* in_sizes, int n_in,
                              void* d_out, int out_size, void* d_ws, size_t ws_size,
                              hipStream_t stream) {
  const float* x  = (const float*)d_in[0];
  const float* tg = (const float*)d_in[1];
  float* out = (float*)d_out;
  const int B = in_sizes[0] / DD;   // 2048
  const int N = in_sizes[1] / DD;   // 50000

  const int    Npad = (N + NT - 1) & ~(NT - 1);   // multiple of 256 (and of 16)
  const int    TT   = Npad / NTT;                 // MFMA tiles (3136)
  const size_t t2e  = (size_t)Npad;

  // --- tier 1: MFMA path ---
  const size_t np1       = (size_t)B * CH2 * KNN;
  const size_t tcvt_u16  = (size_t)TT * 2048;
  const size_t need_mfma = t2e * 4 + np1 * 8 + tcvt_u16 * 2;
  // --- tier 2: VALU path ---
  const size_t np2       = (size_t)B * CH * KNN;
  const size_t need_valu = (t2e + 2 * np2) * 4;

  if (ws_size >= need_mfma && (B % QBB) == 0) {
    float*          t2   = (float*)d_ws;
    float*          pd   = t2 + t2e;
    int*            pi   = (int*)(pd + np1);
    unsigned short* tcvt = (unsigned short*)(pi + np1);
    sqnorm_kernel<<<dim3(Npad / 16), dim3(256), 0, stream>>>(tg, t2, N, Npad);
    cvt_kernel<<<dim3((TT + 3) / 4), dim3(256), 0, stream>>>(tg, tcvt, N, TT);
    knn_mfma_kernel<<<dim3(CH2, B / QBB), dim3(256), 0, stream>>>(x, tcvt, t2, pd, pi, TT);
    merge_kernel<<<dim3(B), dim3(64), 0, stream>>>(tg, pd, pi, out, CH2);
  } else if (ws_size >= need_valu && (B % QB) == 0) {
    float* t2 = (float*)d_ws;
    float* pd = t2 + t2e;
    int*   pi = (int*)(pd + np2);
    sqnorm_kernel<<<dim3(Npad / 16), dim3(256), 0, stream>>>(tg, t2, N, Npad);
    knn_partial_kernel<<<dim3(CH, B / QB), dim3(BLK), 0, stream>>>(x, tg, t2, pd, pi, N);
    merge_kernel<<<dim3(B), dim3(64), 0, stream>>>(tg, pd, pi, out, CH);
  } else {
    knn_fallback<<<dim3(B), dim3(256), 0, stream>>>(x, tg, out, N);
  }
}

// Round 5
// 397.250 us; speedup vs baseline: 2.8593x; 1.0719x over previous
//
#include <hip/hip_runtime.h>

// KNN (k=5, LARGEST distances per faithful-to-source quirk) + gather-mean.
// x: [B=2048, 64] f32, target: [N=50000, 64] f32, out: [B, 64] f32.
//
// Tier-1 (MFMA): distance GEMM via f16 hi/lo split (error ~4e-6, fp32-grade):
//   x = hi + lo*2^-12 (lo stored pre-scaled by 2^12 to stay in f16 normal range)
//   dot = hh + 2^-12*(hl + lh) + 2^-24*ll   -> 8 mfma_f32_16x16x32_f16 / tile
// Selection key (min-semantics): acc = dot - t2/2  (= -r2/2; min acc == max d2).
// -t2/2 is folded into the MFMA accumulator init; t2 is register-prefetched one
// phase ahead (round-4 counters showed its L2 latency exposed per tile).
// Hot-path compare is strict float < : per-lane candidate stream has ascending
// idx, so lexicographic (val,idx) tie-break reduces exactly to value-only.
// Padded target rows: t2 = -1e30 -> acc = +5e29, never selected under min.

typedef _Float16 f16x8 __attribute__((ext_vector_type(8)));
typedef float    f32x4 __attribute__((ext_vector_type(4)));

constexpr int KNN = 5;
constexpr int DD  = 64;    // feature dim
constexpr int NTT = 16;    // targets per MFMA tile
constexpr int GT  = 4;     // tiles staged per phase (barrier per 4 tiles)
constexpr int QBB = 128;   // queries per block (8 waves x 16)

// tier-2 (VALU) constants — round-3 kernel kept as fallback
constexpr int TQ  = 4;
constexpr int QB  = 32;
constexpr int NT  = 256;
constexpr int KC  = 16;
constexpr int CH  = 16;
constexpr int BLK = 512;

__device__ __forceinline__ bool pair_gt(float ad, int ai, float bd, int bi) {
  return (ad > bd) || (ad == bd && ai < bi);
}
__device__ __forceinline__ bool pair_lt(float ad, int ai, float bd, int bi) {
  return (ad < bd) || (ad == bd && ai < bi);
}

// max-semantics sorted insert (tier-2 path)
__device__ __forceinline__ void top5_insert(float d2, int idx,
    float& t0d, float& t1d, float& t2d, float& t3d, float& t4d,
    int&   t0i, int&   t1i, int&   t2i, int&   t3i, int&   t4i) {
  const bool b3 = pair_gt(d2, idx, t3d, t3i);
  const bool b2 = pair_gt(d2, idx, t2d, t2i);
  const bool b1 = pair_gt(d2, idx, t1d, t1i);
  const bool b0 = pair_gt(d2, idx, t0d, t0i);
  t4d = b3 ? t3d : d2;               t4i = b3 ? t3i : idx;
  t3d = b3 ? (b2 ? t2d : d2) : t3d;  t3i = b3 ? (b2 ? t2i : idx) : t3i;
  t2d = b2 ? (b1 ? t1d : d2) : t2d;  t2i = b2 ? (b1 ? t1i : idx) : t2i;
  t1d = b1 ? (b0 ? t0d : d2) : t1d;  t1i = b1 ? (b0 ? t0i : idx) : t1i;
  t0d = b0 ? d2 : t0d;               t0i = b0 ? idx : t0i;
}

// min-semantics sorted insert, value-only compares (tier-1 hot path)
__device__ __forceinline__ void bot5_insert(float v, int idx,
    float& t0d, float& t1d, float& t2d, float& t3d, float& t4d,
    int&   t0i, int&   t1i, int&   t2i, int&   t3i, int&   t4i) {
  const bool b3 = v < t3d;
  const bool b2 = v < t2d;
  const bool b1 = v < t1d;
  const bool b0 = v < t0d;
  t4d = b3 ? t3d : v;                t4i = b3 ? t3i : idx;
  t3d = b3 ? (b2 ? t2d : v) : t3d;   t3i = b3 ? (b2 ? t2i : idx) : t3i;
  t2d = b2 ? (b1 ? t1d : v) : t2d;   t2i = b2 ? (b1 ? t1i : idx) : t2i;
  t1d = b1 ? (b0 ? t0d : v) : t1d;   t1i = b1 ? (b0 ? t0i : idx) : t1i;
  t0d = b0 ? v : t0d;                t0i = b0 ? idx : t0i;
}

__device__ __forceinline__ void gload16(const void* g, void* l) {
  __builtin_amdgcn_global_load_lds(
      (const __attribute__((address_space(1))) unsigned int*)g,
      (__attribute__((address_space(3))) unsigned int*)l, 16, 0, 0);
}

// ---------------- Kernel A: per-target squared norm; pad rows = -1e30 ----------------
__launch_bounds__(256)
__global__ void sqnorm_kernel(const float* __restrict__ tg,
                              float* __restrict__ t2, int N, int Npad) {
  const int tid  = threadIdx.x;
  const int lane = tid & 63;
  const int wv   = tid >> 6;
  const int row  = blockIdx.x * 16 + wv * 4 + (lane >> 4);
  const int f4   = lane & 15;
  if (row >= Npad) return;
  float s = -1e30f;
  if (row < N) {
    const float4 v = reinterpret_cast<const float4*>(tg)[(size_t)row * 16 + f4];
    s = v.x*v.x + v.y*v.y + v.z*v.z + v.w*v.w;
    s += __shfl_xor(s, 1);
    s += __shfl_xor(s, 2);
    s += __shfl_xor(s, 4);
    s += __shfl_xor(s, 8);
  }
  if (f4 == 0) t2[row] = s;
}

// ------------- Kernel A2: convert targets to f16 hi/lo tile image -------------
// Layout per tile (4096 B): [term(2)][kb(8)][col(16)][i(8)] f16;  k = kb*8+i.
__launch_bounds__(256)
__global__ void cvt_kernel(const float* __restrict__ tg,
                           unsigned short* __restrict__ tcvt,
                           int N, int TT) {
  const int tid  = threadIdx.x;
  const int lane = tid & 63;
  const int w    = __builtin_amdgcn_readfirstlane(tid >> 6);
  const int t    = blockIdx.x * 4 + w;          // tile index
  if (t >= TT) return;
  const int col   = lane & 15;
  const int khalf = lane >> 4;                  // 0..3
  const int row   = t * NTT + col;              // global target row
  #pragma unroll
  for (int j = 0; j < 2; ++j) {
    const int kb = khalf * 2 + j;               // 0..7
    float v[8];
    if (row < N) {
      const float4 a = *reinterpret_cast<const float4*>(tg + (size_t)row * DD + kb * 8);
      const float4 b = *reinterpret_cast<const float4*>(tg + (size_t)row * DD + kb * 8 + 4);
      v[0]=a.x; v[1]=a.y; v[2]=a.z; v[3]=a.w;
      v[4]=b.x; v[5]=b.y; v[6]=b.z; v[7]=b.w;
    } else {
      #pragma unroll
      for (int i = 0; i < 8; ++i) v[i] = 0.0f;
    }
    f16x8 hv, lv;
    #pragma unroll
    for (int i = 0; i < 8; ++i) {
      const _Float16 h = (_Float16)v[i];
      hv[i] = h;
      lv[i] = (_Float16)((v[i] - (float)h) * 4096.0f);
    }
    const size_t off = (size_t)t * 2048 + kb * 128 + col * 8;  // ushort units
    *reinterpret_cast<f16x8*>(tcvt + off)        = hv;
    *reinterpret_cast<f16x8*>(tcvt + off + 1024) = lv;
  }
}

// ---------------- Kernel B (MFMA): distances + per-(query,chunk) bottom-5 acc ----------------
__launch_bounds__(512)
__global__ void knn_mfma_kernel(const float* __restrict__ x,
                                const unsigned short* __restrict__ tcvt,
                                const float* __restrict__ t2w,
                                float* __restrict__ pd,
                                int*   __restrict__ pi,
                                int TT, int CHN) {
  __shared__ unsigned short sbuf[2][GT * 2048];  // 32 KiB, double-buffered

  const int tid  = threadIdx.x;
  const int lane = tid & 63;
  const int w    = __builtin_amdgcn_readfirstlane(tid >> 6);
  const int ci   = blockIdx.x;                  // target chunk
  const int q0w  = blockIdx.y * QBB + w * 16;   // wave's first query
  const int col  = lane & 15;
  const int kb   = lane >> 4;                   // 0..3
  const int soff = (tid & 255) * 8;             // staging offset within a tile (ushorts)
  const int sg   = tid >> 8;                    // staging tile pair base (0 or 1)

  // ---- A fragments: 16 queries x 64 d, f16 hi/lo, held in regs all kernel ----
  f16x8 ah[2], al[2];
  #pragma unroll
  for (int c = 0; c < 2; ++c) {
    const float* xp = x + (size_t)(q0w + col) * DD + c * 32 + kb * 8;
    const float4 a = *reinterpret_cast<const float4*>(xp);
    const float4 b = *reinterpret_cast<const float4*>(xp + 4);
    float v[8] = {a.x, a.y, a.z, a.w, b.x, b.y, b.z, b.w};
    #pragma unroll
    for (int i = 0; i < 8; ++i) {
      const _Float16 h = (_Float16)v[i];
      ah[c][i] = h;
      al[c][i] = (_Float16)((v[i] - (float)h) * 4096.0f);
    }
  }

  // per-lane bottom-5 (ascending) per C-reg slot (4 queries/lane)
  float td0[4], td1[4], td2[4], td3[4], td4[4];
  int   ti0[4], ti1[4], ti2[4], ti3[4], ti4[4];
  #pragma unroll
  for (int r = 0; r < 4; ++r) {
    td0[r]=td1[r]=td2[r]=td3[r]=td4[r] = 1e30f;
    ti0[r]=ti1[r]=ti2[r]=ti3[r]=ti4[r] = 0;
  }

  const int tiles = TT / CHN;                   // TT is a multiple of CHN
  const int NP = (tiles + GT - 1) / GT;

  // ---- prologue: stage phase 0 (tiles 0..GT-1) + t2 prefetch ----
  float t2cur[GT], t2nxt[GT];
  #pragma unroll
  for (int s = 0; s < 2; ++s) {
    const int g = sg + s * 2;
    if (g < tiles)
      gload16(tcvt + (size_t)(ci + g * CHN) * 2048 + soff, &sbuf[0][g * 2048 + soff]);
  }
  #pragma unroll
  for (int g = 0; g < GT; ++g)
    t2cur[g] = (g < tiles) ? t2w[(ci + g * CHN) * NTT + col] : 1e30f;
  __syncthreads();

  const int lbase = kb * 256 + col * 16;        // byte offset of lane's B frag in tile

  for (int p = 0; p < NP; ++p) {
    const int bp = p & 1;
    // 1) stage phase p+1 (LDS tiles via global_load_lds; t2 into regs)
    if (p + 1 < NP) {
      #pragma unroll
      for (int s = 0; s < 2; ++s) {
        const int g = sg + s * 2;
        const int j = (p + 1) * GT + g;
        if (j < tiles)
          gload16(tcvt + (size_t)(ci + j * CHN) * 2048 + soff,
                  &sbuf[bp ^ 1][g * 2048 + soff]);
      }
      #pragma unroll
      for (int g = 0; g < GT; ++g) {
        const int j = (p + 1) * GT + g;
        t2nxt[g] = (j < tiles) ? t2w[(ci + j * CHN) * NTT + col] : 1e30f;
      }
    }
    // 2) compute phase p
    #pragma unroll
    for (int g = 0; g < GT; ++g) {
      const int j = p * GT + g;
      if (j < tiles) {
        const int ti = ci + j * CHN;
        const char* tb = (const char*)&sbuf[bp][g * 2048];
        const f16x8 bh0 = *reinterpret_cast<const f16x8*>(tb + lbase);
        const f16x8 bh1 = *reinterpret_cast<const f16x8*>(tb + lbase + 1024);
        const f16x8 bl0 = *reinterpret_cast<const f16x8*>(tb + lbase + 2048);
        const f16x8 bl1 = *reinterpret_cast<const f16x8*>(tb + lbase + 3072);
        const float hv = -0.5f * t2cur[g];
        f32x4 acc_hh = {hv, hv, hv, hv};        // -t2/2 folded into accumulator
        f32x4 acc_m  = {0.f, 0.f, 0.f, 0.f};
        f32x4 acc_ll = {0.f, 0.f, 0.f, 0.f};
        acc_hh = __builtin_amdgcn_mfma_f32_16x16x32_f16(ah[0], bh0, acc_hh, 0, 0, 0);
        acc_hh = __builtin_amdgcn_mfma_f32_16x16x32_f16(ah[1], bh1, acc_hh, 0, 0, 0);
        acc_m  = __builtin_amdgcn_mfma_f32_16x16x32_f16(ah[0], bl0, acc_m, 0, 0, 0);
        acc_m  = __builtin_amdgcn_mfma_f32_16x16x32_f16(ah[1], bl1, acc_m, 0, 0, 0);
        acc_m  = __builtin_amdgcn_mfma_f32_16x16x32_f16(al[0], bh0, acc_m, 0, 0, 0);
        acc_m  = __builtin_amdgcn_mfma_f32_16x16x32_f16(al[1], bh1, acc_m, 0, 0, 0);
        acc_ll = __builtin_amdgcn_mfma_f32_16x16x32_f16(al[0], bl0, acc_ll, 0, 0, 0);
        acc_ll = __builtin_amdgcn_mfma_f32_16x16x32_f16(al[1], bl1, acc_ll, 0, 0, 0);
        const int idx = ti * NTT + col;
        #pragma unroll
        for (int r = 0; r < 4; ++r) {
          float v = fmaf(acc_m[r], 0x1p-12f, acc_hh[r]);
          v = fmaf(acc_ll[r], 0x1p-24f, v);     // v = dot - t2/2  (min == farthest)
          if (v < td4[r])
            bot5_insert(v, idx,
                        td0[r], td1[r], td2[r], td3[r], td4[r],
                        ti0[r], ti1[r], ti2[r], ti3[r], ti4[r]);
        }
      }
    }
    #pragma unroll
    for (int g = 0; g < GT; ++g) t2cur[g] = t2nxt[g];
    __syncthreads();
  }

  // ---- merge within each 16-lane group; write NEGATED keys (max-merge reuse) ----
  #pragma unroll
  for (int r = 0; r < 4; ++r) {
    float rd[KNN]; int ri[KNN];
    #pragma unroll
    for (int rr = 0; rr < KNN; ++rr) {
      float md = td0[r]; int mi = ti0[r];
      #pragma unroll
      for (int k = 1; k < 16; k <<= 1) {
        const float od = __shfl_xor(md, k);
        const int   oi = __shfl_xor(mi, k);
        if (pair_lt(od, oi, md, mi)) { md = od; mi = oi; }
      }
      rd[rr] = md; ri[rr] = mi;
      if (ti0[r] == mi && td0[r] == md) {
        td0[r]=td1[r]; ti0[r]=ti1[r];
        td1[r]=td2[r]; ti1[r]=ti2[r];
        td2[r]=td3[r]; ti2[r]=ti3[r];
        td3[r]=td4[r]; ti3[r]=ti4[r];
        td4[r]=1e30f;  ti4[r]=0;
      }
    }
    if (col == 0) {
      const int q = q0w + (lane >> 4) * 4 + r;
      const int pbase = q * (CHN * KNN) + ci * KNN;
      #pragma unroll
      for (int rr = 0; rr < KNN; ++rr) { pd[pbase + rr] = -rd[rr]; pi[pbase + rr] = ri[rr]; }
    }
  }
}

// ---------------- Kernel C: merge partials (up to 320 cands), gather, mean ----------------
__launch_bounds__(64)
__global__ void merge_kernel(const float* __restrict__ tg,
                             const float* __restrict__ pd,
                             const int*   __restrict__ pi,
                             float* __restrict__ out, int chn) {
  const int q    = blockIdx.x;
  const int lane = threadIdx.x;   // 64 threads
  const int M    = chn * KNN;     // up to 320 candidates
  const int pb   = q * M;
  float cd[5]; int cix[5];
  #pragma unroll
  for (int s = 0; s < 5; ++s) {
    const int i = lane + s * 64;
    const bool v = i < M;
    cd[s]  = v ? pd[pb + i] : -1e30f;
    cix[s] = v ? pi[pb + i] : 0;
  }
  int sel[KNN];
  #pragma unroll
  for (int r = 0; r < KNN; ++r) {
    float md = cd[0]; int mi = cix[0];
    #pragma unroll
    for (int s = 1; s < 5; ++s)
      if (pair_gt(cd[s], cix[s], md, mi)) { md = cd[s]; mi = cix[s]; }
    #pragma unroll
    for (int k = 1; k < 64; k <<= 1) {
      const float od = __shfl_xor(md, k);
      const int   oi = __shfl_xor(mi, k);
      if (pair_gt(od, oi, md, mi)) { md = od; mi = oi; }
    }
    sel[r] = mi;
    #pragma unroll
    for (int s = 0; s < 5; ++s)
      if (cix[s] == mi && cd[s] == md) cd[s] = -1e30f;
  }
  float s = 0.0f;
  #pragma unroll
  for (int r = 0; r < KNN; ++r) s += tg[(size_t)sel[r] * DD + lane];
  out[(size_t)q * DD + lane] = s / 5.0f;
}

// ---------------- Tier-2 (round-3 VALU kernel, fallback if ws too small) ----------------
__launch_bounds__(BLK)
__global__ void knn_partial_kernel(const float* __restrict__ x,
                                   const float* __restrict__ tg,
                                   const float* __restrict__ t2w,
                                   float* __restrict__ pd,
                                   int*   __restrict__ pi,
                                   int N) {
  __shared__ float tbuf[2][KC][NT];

  const int tid  = threadIdx.x;
  const int lane = tid & 63;
  const int w    = __builtin_amdgcn_readfirstlane(tid >> 6);
  const int ci   = blockIdx.x;
  const int q0   = blockIdx.y * QB + w * TQ;
  const float* xq = x + (size_t)q0 * DD;

  float td0[TQ], td1[TQ], td2[TQ], td3[TQ], td4[TQ];
  int   ti0[TQ], ti1[TQ], ti2[TQ], ti3[TQ], ti4[TQ];
  #pragma unroll
  for (int qi = 0; qi < TQ; ++qi) {
    td0[qi]=td1[qi]=td2[qi]=td3[qi]=td4[qi] = -1e30f;
    ti0[qi]=ti1[qi]=ti2[qi]=ti3[qi]=ti4[qi] = 0;
  }

  float acc[TQ][4];
  const int total_tiles = (N + NT - 1) / NT;
  const int mytiles = (ci < total_tiles) ? ((total_tiles - 1 - ci) / CH + 1) : 0;
  const int C = mytiles * 4;

  float4 sva = make_float4(0,0,0,0), svb = make_float4(0,0,0,0);
  const int n0  = tid & 255;
  const int j40 = tid >> 8;
  const int j41 = j40 + 2;
  const float4* tgv = reinterpret_cast<const float4*>(tg);

  if (C > 0) {
    const long r0 = (long)ci * NT + n0;
    if (r0 < N) { sva = tgv[r0 * 16 + j40]; svb = tgv[r0 * 16 + j41]; }
    tbuf[0][j40*4+0][n0] = sva.x;  tbuf[0][j40*4+1][n0] = sva.y;
    tbuf[0][j40*4+2][n0] = sva.z;  tbuf[0][j40*4+3][n0] = sva.w;
    tbuf[0][j41*4+0][n0] = svb.x;  tbuf[0][j41*4+1][n0] = svb.y;
    tbuf[0][j41*4+2][n0] = svb.z;  tbuf[0][j41*4+3][n0] = svb.w;
  }
  __syncthreads();

  for (int c = 0; c < C; ++c) {
    const int b       = c & 1;
    const int kc      = c & 3;
    const int tileidx = ci + (c >> 2) * CH;
    const bool more   = (c + 1 < C);

    if (more) {
      const int gc2   = c + 1;
      const int kc2   = gc2 & 3;
      const int tile2 = ci + (gc2 >> 2) * CH;
      const long r0n  = (long)tile2 * NT + n0;
      sva = make_float4(0,0,0,0);
      svb = make_float4(0,0,0,0);
      if (r0n < N) {
        sva = tgv[r0n * 16 + kc2 * 4 + j40];
        svb = tgv[r0n * 16 + kc2 * 4 + j41];
      }
    }

    if (kc == 0) {
      #pragma unroll
      for (int qi = 0; qi < TQ; ++qi) {
        acc[qi][0]=0.f; acc[qi][1]=0.f; acc[qi][2]=0.f; acc[qi][3]=0.f;
      }
    }
    #pragma unroll
    for (int h = 0; h < 2; ++h) {
      const int dbase = kc * KC + h * 8;
      float qs[TQ][8];
      #pragma unroll
      for (int qi = 0; qi < TQ; ++qi) {
        const float4 qa = *reinterpret_cast<const float4*>(xq + qi * DD + dbase);
        const float4 qb = *reinterpret_cast<const float4*>(xq + qi * DD + dbase + 4);
        qs[qi][0]=qa.x; qs[qi][1]=qa.y; qs[qi][2]=qa.z; qs[qi][3]=qa.w;
        qs[qi][4]=qb.x; qs[qi][5]=qb.y; qs[qi][6]=qb.z; qs[qi][7]=qb.w;
      }
      #pragma unroll
      for (int dd = 0; dd < 8; ++dd) {
        const float4 tv = *reinterpret_cast<const float4*>(&tbuf[b][h*8+dd][lane*4]);
        #pragma unroll
        for (int qi = 0; qi < TQ; ++qi) {
          acc[qi][0] = fmaf(qs[qi][dd], tv.x, acc[qi][0]);
          acc[qi][1] = fmaf(qs[qi][dd], tv.y, acc[qi][1]);
          acc[qi][2] = fmaf(qs[qi][dd], tv.z, acc[qi][2]);
          acc[qi][3] = fmaf(qs[qi][dd], tv.w, acc[qi][3]);
        }
      }
    }

    if (kc == 3) {
      const int nb = tileidx * NT + lane * 4;
      const float4 t2v = *reinterpret_cast<const float4*>(t2w + nb);
      const float t2a[4] = { t2v.x, t2v.y, t2v.z, t2v.w };
      #pragma unroll
      for (int qi = 0; qi < TQ; ++qi) {
        #pragma unroll
        for (int j = 0; j < 4; ++j) {
          const float r2  = fmaf(-2.0f, acc[qi][j], t2a[j]);
          const int   idx = nb + j;
          if (idx < N && pair_gt(r2, idx, td4[qi], ti4[qi]))
            top5_insert(r2, idx,
                        td0[qi], td1[qi], td2[qi], td3[qi], td4[qi],
                        ti0[qi], ti1[qi], ti2[qi], ti3[qi], ti4[qi]);
        }
      }
    }

    if (more) {
      const int bo = (c + 1) & 1;
      tbuf[bo][j40*4+0][n0] = sva.x;  tbuf[bo][j40*4+1][n0] = sva.y;
      tbuf[bo][j40*4+2][n0] = sva.z;  tbuf[bo][j40*4+3][n0] = sva.w;
      tbuf[bo][j41*4+0][n0] = svb.x;  tbuf[bo][j41*4+1][n0] = svb.y;
      tbuf[bo][j41*4+2][n0] = svb.z;  tbuf[bo][j41*4+3][n0] = svb.w;
    }
    __syncthreads();
  }

  #pragma unroll
  for (int qi = 0; qi < TQ; ++qi) {
    float rd[KNN]; int ri[KNN];
    #pragma unroll
    for (int r = 0; r < KNN; ++r) {
      float md = td0[qi]; int mi = ti0[qi];
      #pragma unroll
      for (int k = 1; k < 64; k <<= 1) {
        const float od = __shfl_xor(md, k);
        const int   oi = __shfl_xor(mi, k);
        if (pair_gt(od, oi, md, mi)) { md = od; mi = oi; }
      }
      rd[r] = md; ri[r] = mi;
      if (ti0[qi] == mi && td0[qi] == md) {
        td0[qi]=td1[qi]; ti0[qi]=ti1[qi];
        td1[qi]=td2[qi]; ti1[qi]=ti2[qi];
        td2[qi]=td3[qi]; ti2[qi]=ti3[qi];
        td3[qi]=td4[qi]; ti3[qi]=ti4[qi];
        td4[qi]=-1e30f;  ti4[qi]=0;
      }
    }
    if (lane == 0) {
      const int pbase = (q0 + qi) * (CH * KNN) + ci * KNN;
      #pragma unroll
      for (int r = 0; r < KNN; ++r) { pd[pbase + r] = rd[r]; pi[pbase + r] = ri[r]; }
    }
  }
}

// ---------------- Tier-3 fallback ----------------
__launch_bounds__(256)
__global__ void knn_fallback(const float* __restrict__ x,
                             const float* __restrict__ tg,
                             float* __restrict__ out, int N) {
  const int q   = blockIdx.x;
  const int tid = threadIdx.x;
  __shared__ float qsh[DD];
  __shared__ float smd[KNN][256];
  __shared__ int   smi[KNN][256];
  if (tid < DD) qsh[tid] = x[(size_t)q * DD + tid];
  __syncthreads();
  float qv[DD];
  #pragma unroll
  for (int d = 0; d < DD; ++d) qv[d] = qsh[d];
  float x2 = 0.0f;
  #pragma unroll
  for (int d = 0; d < DD; ++d) x2 = fmaf(qv[d], qv[d], x2);
  float a0=-1e30f,a1=-1e30f,a2=-1e30f,a3=-1e30f,a4=-1e30f;
  int   i0=0,i1=0,i2=0,i3=0,i4=0;
  for (int n = tid; n < N; n += 256) {
    const float4* tr = reinterpret_cast<const float4*>(tg + (size_t)n * DD);
    float dot = 0.0f, tt = 0.0f;
    #pragma unroll
    for (int k = 0; k < 16; ++k) {
      const float4 tv = tr[k];
      dot = fmaf(qv[4*k+0], tv.x, dot); tt = fmaf(tv.x, tv.x, tt);
      dot = fmaf(qv[4*k+1], tv.y, dot); tt = fmaf(tv.y, tv.y, tt);
      dot = fmaf(qv[4*k+2], tv.z, dot); tt = fmaf(tv.z, tv.z, tt);
      dot = fmaf(qv[4*k+3], tv.w, dot); tt = fmaf(tv.w, tv.w, tt);
    }
    const float d2 = fmaf(-2.0f, dot, x2 + tt);
    if (pair_gt(d2, n, a4, i4))
      top5_insert(d2, n, a0,a1,a2,a3,a4, i0,i1,i2,i3,i4);
  }
  smd[0][tid]=a0; smi[0][tid]=i0;  smd[1][tid]=a1; smi[1][tid]=i1;
  smd[2][tid]=a2; smi[2][tid]=i2;  smd[3][tid]=a3; smi[3][tid]=i3;
  smd[4][tid]=a4; smi[4][tid]=i4;
  __syncthreads();
  if (tid < 64) {
    a0=a1=a2=a3=a4=-1e30f; i0=i1=i2=i3=i4=0;
    for (int src = tid; src < 256; src += 64) {
      #pragma unroll
      for (int r = 0; r < KNN; ++r) {
        const float dd2 = smd[r][src]; const int ii = smi[r][src];
        if (pair_gt(dd2, ii, a4, i4))
          top5_insert(dd2, ii, a0,a1,a2,a3,a4, i0,i1,i2,i3,i4);
      }
    }
    int sel[KNN];
    #pragma unroll
    for (int r = 0; r < KNN; ++r) {
      float md = a0; int mi = i0;
      #pragma unroll
      for (int k = 1; k < 64; k <<= 1) {
        const float od = __shfl_xor(md, k);
        const int   oi = __shfl_xor(mi, k);
        if (pair_gt(od, oi, md, mi)) { md = od; mi = oi; }
      }
      sel[r] = mi;
      if (i0 == mi && a0 == md) {
        a0=a1; i0=i1; a1=a2; i1=i2; a2=a3; i2=i3; a3=a4; i3=i4; a4=-1e30f; i4=0;
      }
    }
    float s = 0.0f;
    #pragma unroll
    for (int r = 0; r < KNN; ++r) s += tg[(size_t)sel[r] * DD + tid];
    out[(size_t)q * DD + tid] = s / 5.0f;
  }
}

extern "C" void kernel_launch(void* const* d_in, const int* in_sizes, int n_in,
                              void* d_out, int out_size, void* d_ws, size_t ws_size,
                              hipStream_t stream) {
  const float* x  = (const float*)d_in[0];
  const float* tg = (const float*)d_in[1];
  float* out = (float*)d_out;
  const int B = in_sizes[0] / DD;   // 2048
  const int N = in_sizes[1] / DD;   // 50000

  const int    Npad = (N + 1023) & ~1023;        // multiple of 1024 => TT % 64 == 0
  const int    TT   = Npad / NTT;                // MFMA tiles (3136)
  const size_t t2e  = (size_t)Npad;

  // tier-1 workspace needs, by chunk count
  const size_t tcvt_u16 = (size_t)TT * 2048;
  auto need1 = [&](int chn) {
    return t2e * 4 + (size_t)B * chn * KNN * 8 + tcvt_u16 * 2;
  };
  // tier-2
  const size_t np2       = (size_t)B * CH * KNN;
  const size_t need_valu = (t2e + 2 * np2) * 4;

  int CHN = 0;
  if (ws_size >= need1(64)) CHN = 64;
  else if (ws_size >= need1(32)) CHN = 32;

  if (CHN > 0 && (B % QBB) == 0) {
    const size_t np1 = (size_t)B * CHN * KNN;
    float*          t2   = (float*)d_ws;
    float*          pd   = t2 + t2e;
    int*            pi   = (int*)(pd + np1);
    unsigned short* tcvt = (unsigned short*)(pi + np1);
    sqnorm_kernel<<<dim3(Npad / 16), dim3(256), 0, stream>>>(tg, t2, N, Npad);
    cvt_kernel<<<dim3((TT + 3) / 4), dim3(256), 0, stream>>>(tg, tcvt, N, TT);
    knn_mfma_kernel<<<dim3(CHN, B / QBB), dim3(512), 0, stream>>>(x, tcvt, t2, pd, pi, TT, CHN);
    merge_kernel<<<dim3(B), dim3(64), 0, stream>>>(tg, pd, pi, out, CHN);
  } else if (ws_size >= need_valu && (B % QB) == 0) {
    float* t2 = (float*)d_ws;
    float* pd = t2 + t2e;
    int*   pi = (int*)(pd + np2);
    sqnorm_kernel<<<dim3(Npad / 16), dim3(256), 0, stream>>>(tg, t2, N, Npad);
    knn_partial_kernel<<<dim3(CH, B / QB), dim3(BLK), 0, stream>>>(x, tg, t2, pd, pi, N);
    merge_kernel<<<dim3(B), dim3(64), 0, stream>>>(tg, pd, pi, out, CH);
  } else {
    knn_fallback<<<dim3(B), dim3(256), 0, stream>>>(x, tg, out, N);
  }
}

// Round 6
// 263.385 us; speedup vs baseline: 4.3125x; 1.5082x over previous
//
#include <hip/hip_runtime.h>

// KNN (k=5, LARGEST distances per faithful-to-source quirk) + gather-mean.
// x: [B=2048, 64] f32, target: [N=50000, 64] f32, out: [B, 64] f32.
//
// Tier-1 (MFMA): distance GEMM via f16 hi/lo split (error ~4e-6, fp32-grade):
//   x = hi + lo*2^-12 (lo pre-scaled by 2^12 to stay in f16 normal range)
//   dot = hh + 2^-12*(hl + lh) + 2^-24*ll   -> 8 mfma_f32_16x16x32_f16 / tile
// Selection key (min-semantics): v = dot - t2/2 (= -r2/2; min v == max dist).
// Round-6: branchless unconditional bottom-5 insert (round-5 counters: the
// guarded insert body issued every tile anyway — union over 256 streams ≈ 1 —
// plus divergence overhead), fully uniform loops (Npad multiple of CHN*GT*16),
// chunk-contiguous t2 image (imm-offset prefetch), 256-thread blocks for
// 2-2.5x wave residency.

typedef _Float16 f16x8 __attribute__((ext_vector_type(8)));
typedef float    f32x4 __attribute__((ext_vector_type(4)));

constexpr int KNN = 5;
constexpr int DD  = 64;    // feature dim
constexpr int NTT = 16;    // targets per MFMA tile
constexpr int GT  = 4;     // tiles per phase (one barrier per 4 tiles)
constexpr int QBB = 64;    // queries per block (4 waves x 16)

// tier-2 (VALU) constants — round-3 kernel kept as fallback
constexpr int TQ  = 4;
constexpr int QB  = 32;
constexpr int NT  = 256;
constexpr int KC  = 16;
constexpr int CH  = 16;
constexpr int BLK = 512;

__device__ __forceinline__ bool pair_gt(float ad, int ai, float bd, int bi) {
  return (ad > bd) || (ad == bd && ai < bi);
}
__device__ __forceinline__ bool pair_lt(float ad, int ai, float bd, int bi) {
  return (ad < bd) || (ad == bd && ai < bi);
}

// max-semantics sorted insert (tier-2/3 paths)
__device__ __forceinline__ void top5_insert(float d2, int idx,
    float& t0d, float& t1d, float& t2d, float& t3d, float& t4d,
    int&   t0i, int&   t1i, int&   t2i, int&   t3i, int&   t4i) {
  const bool b3 = pair_gt(d2, idx, t3d, t3i);
  const bool b2 = pair_gt(d2, idx, t2d, t2i);
  const bool b1 = pair_gt(d2, idx, t1d, t1i);
  const bool b0 = pair_gt(d2, idx, t0d, t0i);
  t4d = b3 ? t3d : d2;               t4i = b3 ? t3i : idx;
  t3d = b3 ? (b2 ? t2d : d2) : t3d;  t3i = b3 ? (b2 ? t2i : idx) : t3i;
  t2d = b2 ? (b1 ? t1d : d2) : t2d;  t2i = b2 ? (b1 ? t1i : idx) : t2i;
  t1d = b1 ? (b0 ? t0d : d2) : t1d;  t1i = b1 ? (b0 ? t0i : idx) : t1i;
  t0d = b0 ? d2 : t0d;               t0i = b0 ? idx : t0i;
}

// min-semantics UNCONDITIONAL branchless insert (tier-1 hot path).
// Sorted ascending t0<=..<=t4. Strict < keeps earlier (= smaller idx) on ties.
__device__ __forceinline__ void bot5_insert_bl(float v, int idx,
    float& t0d, float& t1d, float& t2d, float& t3d, float& t4d,
    int&   t0i, int&   t1i, int&   t2i, int&   t3i, int&   t4i) {
  const bool b0 = v < t0d;
  const bool b1 = v < t1d;
  const bool b2 = v < t2d;
  const bool b3 = v < t3d;
  const bool b4 = v < t4d;
  t4d = b3 ? t3d : (b4 ? v : t4d);  t4i = b3 ? t3i : (b4 ? idx : t4i);
  t3d = b3 ? (b2 ? t2d : v) : t3d;  t3i = b3 ? (b2 ? t2i : idx) : t3i;
  t2d = b2 ? (b1 ? t1d : v) : t2d;  t2i = b2 ? (b1 ? t1i : idx) : t2i;
  t1d = b1 ? (b0 ? t0d : v) : t1d;  t1i = b1 ? (b0 ? t0i : idx) : t1i;
  t0d = b0 ? v : t0d;               t0i = b0 ? idx : t0i;
}

__device__ __forceinline__ void gload16(const void* g, void* l) {
  __builtin_amdgcn_global_load_lds(
      (const __attribute__((address_space(1))) unsigned int*)g,
      (__attribute__((address_space(3))) unsigned int*)l, 16, 0, 0);
}

// ------- Kernel A (tier-1): sqnorm into chunk-contiguous image t2c[ci][j][col] -------
__launch_bounds__(256)
__global__ void sqnorm_chunked(const float* __restrict__ tg,
                               float* __restrict__ t2c,
                               int N, int Npad, int tiles, int chnlog) {
  const int tid  = threadIdx.x;
  const int lane = tid & 63;
  const int wv   = tid >> 6;
  const int row  = blockIdx.x * 16 + wv * 4 + (lane >> 4);
  const int f4   = lane & 15;
  if (row >= Npad) return;
  float s = -1e30f;
  if (row < N) {
    const float4 v = reinterpret_cast<const float4*>(tg)[(size_t)row * 16 + f4];
    s = v.x*v.x + v.y*v.y + v.z*v.z + v.w*v.w;
    s += __shfl_xor(s, 1);
    s += __shfl_xor(s, 2);
    s += __shfl_xor(s, 4);
    s += __shfl_xor(s, 8);
  }
  if (f4 == 0) {
    const int tile = row >> 4;
    const int ci   = tile & ((1 << chnlog) - 1);
    const int j    = tile >> chnlog;
    t2c[((size_t)ci * tiles + j) * 16 + (row & 15)] = s;
  }
}

// ------- Kernel A (tier-2): linear sqnorm (pad rows -1e30) -------
__launch_bounds__(256)
__global__ void sqnorm_kernel(const float* __restrict__ tg,
                              float* __restrict__ t2, int N, int Npad) {
  const int tid  = threadIdx.x;
  const int lane = tid & 63;
  const int wv   = tid >> 6;
  const int row  = blockIdx.x * 16 + wv * 4 + (lane >> 4);
  const int f4   = lane & 15;
  if (row >= Npad) return;
  float s = -1e30f;
  if (row < N) {
    const float4 v = reinterpret_cast<const float4*>(tg)[(size_t)row * 16 + f4];
    s = v.x*v.x + v.y*v.y + v.z*v.z + v.w*v.w;
    s += __shfl_xor(s, 1);
    s += __shfl_xor(s, 2);
    s += __shfl_xor(s, 4);
    s += __shfl_xor(s, 8);
  }
  if (f4 == 0) t2[row] = s;
}

// ------------- Kernel A2: convert targets to f16 hi/lo tile image -------------
// Layout per tile (4096 B): [term(2)][kb(8)][col(16)][i(8)] f16;  k = kb*8+i.
__launch_bounds__(256)
__global__ void cvt_kernel(const float* __restrict__ tg,
                           unsigned short* __restrict__ tcvt,
                           int N, int TT) {
  const int tid  = threadIdx.x;
  const int lane = tid & 63;
  const int w    = __builtin_amdgcn_readfirstlane(tid >> 6);
  const int t    = blockIdx.x * 4 + w;          // tile index
  if (t >= TT) return;
  const int col   = lane & 15;
  const int khalf = lane >> 4;                  // 0..3
  const int row   = t * NTT + col;              // global target row
  #pragma unroll
  for (int j = 0; j < 2; ++j) {
    const int kb = khalf * 2 + j;               // 0..7
    float v[8];
    if (row < N) {
      const float4 a = *reinterpret_cast<const float4*>(tg + (size_t)row * DD + kb * 8);
      const float4 b = *reinterpret_cast<const float4*>(tg + (size_t)row * DD + kb * 8 + 4);
      v[0]=a.x; v[1]=a.y; v[2]=a.z; v[3]=a.w;
      v[4]=b.x; v[5]=b.y; v[6]=b.z; v[7]=b.w;
    } else {
      #pragma unroll
      for (int i = 0; i < 8; ++i) v[i] = 0.0f;
    }
    f16x8 hv, lv;
    #pragma unroll
    for (int i = 0; i < 8; ++i) {
      const _Float16 h = (_Float16)v[i];
      hv[i] = h;
      lv[i] = (_Float16)((v[i] - (float)h) * 4096.0f);
    }
    const size_t off = (size_t)t * 2048 + kb * 128 + col * 8;  // ushort units
    *reinterpret_cast<f16x8*>(tcvt + off)        = hv;
    *reinterpret_cast<f16x8*>(tcvt + off + 1024) = lv;
  }
}

// ---------------- Kernel B (MFMA): distances + per-(query,chunk) bottom-5 ----------------
__launch_bounds__(256)
__global__ void knn_mfma_kernel(const float* __restrict__ x,
                                const unsigned short* __restrict__ tcvt,
                                const float* __restrict__ t2c,
                                float* __restrict__ pd,
                                int*   __restrict__ pi,
                                int tiles, int CHN) {
  __shared__ unsigned short sbuf[2][GT * 2048];  // 32 KiB, double-buffered

  const int tid  = threadIdx.x;
  const int lane = tid & 63;
  const int w    = __builtin_amdgcn_readfirstlane(tid >> 6);
  const int ci   = blockIdx.x;                  // target chunk
  const int q0w  = blockIdx.y * QBB + w * 16;   // wave's first query
  const int col  = lane & 15;
  const int kb   = lane >> 4;                   // 0..3

  // ---- A fragments: 16 queries x 64 d, f16 hi/lo, in regs all kernel ----
  f16x8 ah[2], al[2];
  #pragma unroll
  for (int c = 0; c < 2; ++c) {
    const float* xp = x + (size_t)(q0w + col) * DD + c * 32 + kb * 8;
    const float4 a = *reinterpret_cast<const float4*>(xp);
    const float4 b = *reinterpret_cast<const float4*>(xp + 4);
    float v[8] = {a.x, a.y, a.z, a.w, b.x, b.y, b.z, b.w};
    #pragma unroll
    for (int i = 0; i < 8; ++i) {
      const _Float16 h = (_Float16)v[i];
      ah[c][i] = h;
      al[c][i] = (_Float16)((v[i] - (float)h) * 4096.0f);
    }
  }

  // per-lane bottom-5 per C-reg slot (4 queries/lane)
  float td0[4], td1[4], td2[4], td3[4], td4[4];
  int   ti0[4], ti1[4], ti2[4], ti3[4], ti4[4];
  #pragma unroll
  for (int r = 0; r < 4; ++r) {
    td0[r]=td1[r]=td2[r]=td3[r]=td4[r] = 1e30f;
    ti0[r]=ti1[r]=ti2[r]=ti3[r]=ti4[r] = 0;
  }

  const int NP = tiles / GT;                    // exact (tiles % GT == 0)

  // running pointers
  const size_t tstep = (size_t)CHN * 2048;      // ushorts per j-step
  const unsigned short* gsrc = tcvt + (size_t)ci * 2048 + tid * 8;
  const float* tp  = t2c + (size_t)ci * tiles * 16 + col;

  // ---- prologue: stage phase 0 + t2 ----
  #pragma unroll
  for (int g = 0; g < GT; ++g)
    gload16(gsrc + (size_t)g * tstep, &sbuf[0][g * 2048 + tid * 8]);
  float t2cur[GT], t2nxt[GT];
  #pragma unroll
  for (int g = 0; g < GT; ++g) t2cur[g] = tp[g * 16];
  __syncthreads();

  const unsigned short* gp = gsrc + (size_t)GT * tstep;  // phase p+1 tiles
  const float* tpr = tp + GT * 16;                       // phase p+1 t2
  int idxv = ci * NTT + col;                             // running candidate idx
  const int idxstep = CHN * NTT;
  const int lbase = kb * 256 + col * 16;                 // lane's B-frag byte off

  for (int p = 0; p < NP; ++p) {
    const int bp = p & 1;
    // 1) stage phase p+1
    if (p + 1 < NP) {
      #pragma unroll
      for (int g = 0; g < GT; ++g)
        gload16(gp + (size_t)g * tstep, &sbuf[bp ^ 1][g * 2048 + tid * 8]);
      #pragma unroll
      for (int g = 0; g < GT; ++g) t2nxt[g] = tpr[g * 16];
    }
    // 2) compute phase p (GT uniform tiles)
    #pragma unroll
    for (int g = 0; g < GT; ++g) {
      const char* tb = (const char*)&sbuf[bp][g * 2048];
      const f16x8 bh0 = *reinterpret_cast<const f16x8*>(tb + lbase);
      const f16x8 bh1 = *reinterpret_cast<const f16x8*>(tb + lbase + 1024);
      const f16x8 bl0 = *reinterpret_cast<const f16x8*>(tb + lbase + 2048);
      const f16x8 bl1 = *reinterpret_cast<const f16x8*>(tb + lbase + 3072);
      const float hv = -0.5f * t2cur[g];
      f32x4 acc_hh = {hv, hv, hv, hv};          // -t2/2 folded into accumulator
      f32x4 acc_m  = {0.f, 0.f, 0.f, 0.f};
      f32x4 acc_ll = {0.f, 0.f, 0.f, 0.f};
      acc_hh = __builtin_amdgcn_mfma_f32_16x16x32_f16(ah[0], bh0, acc_hh, 0, 0, 0);
      acc_hh = __builtin_amdgcn_mfma_f32_16x16x32_f16(ah[1], bh1, acc_hh, 0, 0, 0);
      acc_m  = __builtin_amdgcn_mfma_f32_16x16x32_f16(ah[0], bl0, acc_m, 0, 0, 0);
      acc_m  = __builtin_amdgcn_mfma_f32_16x16x32_f16(ah[1], bl1, acc_m, 0, 0, 0);
      acc_m  = __builtin_amdgcn_mfma_f32_16x16x32_f16(al[0], bh0, acc_m, 0, 0, 0);
      acc_m  = __builtin_amdgcn_mfma_f32_16x16x32_f16(al[1], bh1, acc_m, 0, 0, 0);
      acc_ll = __builtin_amdgcn_mfma_f32_16x16x32_f16(al[0], bl0, acc_ll, 0, 0, 0);
      acc_ll = __builtin_amdgcn_mfma_f32_16x16x32_f16(al[1], bl1, acc_ll, 0, 0, 0);
      #pragma unroll
      for (int r = 0; r < 4; ++r) {
        float v = fmaf(acc_m[r], 0x1p-12f, acc_hh[r]);
        v = fmaf(acc_ll[r], 0x1p-24f, v);       // v = dot - t2/2 (min == farthest)
        bot5_insert_bl(v, idxv,
                       td0[r], td1[r], td2[r], td3[r], td4[r],
                       ti0[r], ti1[r], ti2[r], ti3[r], ti4[r]);
      }
      idxv += idxstep;
    }
    #pragma unroll
    for (int g = 0; g < GT; ++g) t2cur[g] = t2nxt[g];
    gp  += (size_t)GT * tstep;
    tpr += GT * 16;
    __syncthreads();
  }

  // ---- merge within each 16-lane group; write NEGATED keys (max-merge reuse) ----
  #pragma unroll
  for (int r = 0; r < 4; ++r) {
    float rd[KNN]; int ri[KNN];
    #pragma unroll
    for (int rr = 0; rr < KNN; ++rr) {
      float md = td0[r]; int mi = ti0[r];
      #pragma unroll
      for (int k = 1; k < 16; k <<= 1) {
        const float od = __shfl_xor(md, k);
        const int   oi = __shfl_xor(mi, k);
        if (pair_lt(od, oi, md, mi)) { md = od; mi = oi; }
      }
      rd[rr] = md; ri[rr] = mi;
      if (ti0[r] == mi && td0[r] == md) {
        td0[r]=td1[r]; ti0[r]=ti1[r];
        td1[r]=td2[r]; ti1[r]=ti2[r];
        td2[r]=td3[r]; ti2[r]=ti3[r];
        td3[r]=td4[r]; ti3[r]=ti4[r];
        td4[r]=1e30f;  ti4[r]=0;
      }
    }
    if (col == 0) {
      const int q = q0w + (lane >> 4) * 4 + r;
      const int pbase = q * (CHN * KNN) + ci * KNN;
      #pragma unroll
      for (int rr = 0; rr < KNN; ++rr) { pd[pbase + rr] = -rd[rr]; pi[pbase + rr] = ri[rr]; }
    }
  }
}

// ---------------- Kernel C: merge partials (up to 320 cands), gather, mean ----------------
__launch_bounds__(64)
__global__ void merge_kernel(const float* __restrict__ tg,
                             const float* __restrict__ pd,
                             const int*   __restrict__ pi,
                             float* __restrict__ out, int chn) {
  const int q    = blockIdx.x;
  const int lane = threadIdx.x;   // 64 threads
  const int M    = chn * KNN;     // up to 320 candidates
  const int pb   = q * M;
  float cd[5]; int cix[5];
  #pragma unroll
  for (int s = 0; s < 5; ++s) {
    const int i = lane + s * 64;
    const bool v = i < M;
    cd[s]  = v ? pd[pb + i] : -1e30f;
    cix[s] = v ? pi[pb + i] : 0;
  }
  int sel[KNN];
  #pragma unroll
  for (int r = 0; r < KNN; ++r) {
    float md = cd[0]; int mi = cix[0];
    #pragma unroll
    for (int s = 1; s < 5; ++s)
      if (pair_gt(cd[s], cix[s], md, mi)) { md = cd[s]; mi = cix[s]; }
    #pragma unroll
    for (int k = 1; k < 64; k <<= 1) {
      const float od = __shfl_xor(md, k);
      const int   oi = __shfl_xor(mi, k);
      if (pair_gt(od, oi, md, mi)) { md = od; mi = oi; }
    }
    sel[r] = mi;
    #pragma unroll
    for (int s = 0; s < 5; ++s)
      if (cix[s] == mi && cd[s] == md) cd[s] = -1e30f;
  }
  float s = 0.0f;
  #pragma unroll
  for (int r = 0; r < KNN; ++r) s += tg[(size_t)sel[r] * DD + lane];
  out[(size_t)q * DD + lane] = s / 5.0f;
}

// ---------------- Tier-2 (round-3 VALU kernel, fallback if ws too small) ----------------
__launch_bounds__(BLK)
__global__ void knn_partial_kernel(const float* __restrict__ x,
                                   const float* __restrict__ tg,
                                   const float* __restrict__ t2w,
                                   float* __restrict__ pd,
                                   int*   __restrict__ pi,
                                   int N) {
  __shared__ float tbuf[2][KC][NT];

  const int tid  = threadIdx.x;
  const int lane = tid & 63;
  const int w    = __builtin_amdgcn_readfirstlane(tid >> 6);
  const int ci   = blockIdx.x;
  const int q0   = blockIdx.y * QB + w * TQ;
  const float* xq = x + (size_t)q0 * DD;

  float td0[TQ], td1[TQ], td2[TQ], td3[TQ], td4[TQ];
  int   ti0[TQ], ti1[TQ], ti2[TQ], ti3[TQ], ti4[TQ];
  #pragma unroll
  for (int qi = 0; qi < TQ; ++qi) {
    td0[qi]=td1[qi]=td2[qi]=td3[qi]=td4[qi] = -1e30f;
    ti0[qi]=ti1[qi]=ti2[qi]=ti3[qi]=ti4[qi] = 0;
  }

  float acc[TQ][4];
  const int total_tiles = (N + NT - 1) / NT;
  const int mytiles = (ci < total_tiles) ? ((total_tiles - 1 - ci) / CH + 1) : 0;
  const int C = mytiles * 4;

  float4 sva = make_float4(0,0,0,0), svb = make_float4(0,0,0,0);
  const int n0  = tid & 255;
  const int j40 = tid >> 8;
  const int j41 = j40 + 2;
  const float4* tgv = reinterpret_cast<const float4*>(tg);

  if (C > 0) {
    const long r0 = (long)ci * NT + n0;
    if (r0 < N) { sva = tgv[r0 * 16 + j40]; svb = tgv[r0 * 16 + j41]; }
    tbuf[0][j40*4+0][n0] = sva.x;  tbuf[0][j40*4+1][n0] = sva.y;
    tbuf[0][j40*4+2][n0] = sva.z;  tbuf[0][j40*4+3][n0] = sva.w;
    tbuf[0][j41*4+0][n0] = svb.x;  tbuf[0][j41*4+1][n0] = svb.y;
    tbuf[0][j41*4+2][n0] = svb.z;  tbuf[0][j41*4+3][n0] = svb.w;
  }
  __syncthreads();

  for (int c = 0; c < C; ++c) {
    const int b       = c & 1;
    const int kc      = c & 3;
    const int tileidx = ci + (c >> 2) * CH;
    const bool more   = (c + 1 < C);

    if (more) {
      const int gc2   = c + 1;
      const int kc2   = gc2 & 3;
      const int tile2 = ci + (gc2 >> 2) * CH;
      const long r0n  = (long)tile2 * NT + n0;
      sva = make_float4(0,0,0,0);
      svb = make_float4(0,0,0,0);
      if (r0n < N) {
        sva = tgv[r0n * 16 + kc2 * 4 + j40];
        svb = tgv[r0n * 16 + kc2 * 4 + j41];
      }
    }

    if (kc == 0) {
      #pragma unroll
      for (int qi = 0; qi < TQ; ++qi) {
        acc[qi][0]=0.f; acc[qi][1]=0.f; acc[qi][2]=0.f; acc[qi][3]=0.f;
      }
    }
    #pragma unroll
    for (int h = 0; h < 2; ++h) {
      const int dbase = kc * KC + h * 8;
      float qs[TQ][8];
      #pragma unroll
      for (int qi = 0; qi < TQ; ++qi) {
        const float4 qa = *reinterpret_cast<const float4*>(xq + qi * DD + dbase);
        const float4 qb = *reinterpret_cast<const float4*>(xq + qi * DD + dbase + 4);
        qs[qi][0]=qa.x; qs[qi][1]=qa.y; qs[qi][2]=qa.z; qs[qi][3]=qa.w;
        qs[qi][4]=qb.x; qs[qi][5]=qb.y; qs[qi][6]=qb.z; qs[qi][7]=qb.w;
      }
      #pragma unroll
      for (int dd = 0; dd < 8; ++dd) {
        const float4 tv = *reinterpret_cast<const float4*>(&tbuf[b][h*8+dd][lane*4]);
        #pragma unroll
        for (int qi = 0; qi < TQ; ++qi) {
          acc[qi][0] = fmaf(qs[qi][dd], tv.x, acc[qi][0]);
          acc[qi][1] = fmaf(qs[qi][dd], tv.y, acc[qi][1]);
          acc[qi][2] = fmaf(qs[qi][dd], tv.z, acc[qi][2]);
          acc[qi][3] = fmaf(qs[qi][dd], tv.w, acc[qi][3]);
        }
      }
    }

    if (kc == 3) {
      const int nb = tileidx * NT + lane * 4;
      const float4 t2v = *reinterpret_cast<const float4*>(t2w + nb);
      const float t2a[4] = { t2v.x, t2v.y, t2v.z, t2v.w };
      #pragma unroll
      for (int qi = 0; qi < TQ; ++qi) {
        #pragma unroll
        for (int j = 0; j < 4; ++j) {
          const float r2  = fmaf(-2.0f, acc[qi][j], t2a[j]);
          const int   idx = nb + j;
          if (idx < N && pair_gt(r2, idx, td4[qi], ti4[qi]))
            top5_insert(r2, idx,
                        td0[qi], td1[qi], td2[qi], td3[qi], td4[qi],
                        ti0[qi], ti1[qi], ti2[qi], ti3[qi], ti4[qi]);
        }
      }
    }

    if (more) {
      const int bo = (c + 1) & 1;
      tbuf[bo][j40*4+0][n0] = sva.x;  tbuf[bo][j40*4+1][n0] = sva.y;
      tbuf[bo][j40*4+2][n0] = sva.z;  tbuf[bo][j40*4+3][n0] = sva.w;
      tbuf[bo][j41*4+0][n0] = svb.x;  tbuf[bo][j41*4+1][n0] = svb.y;
      tbuf[bo][j41*4+2][n0] = svb.z;  tbuf[bo][j41*4+3][n0] = svb.w;
    }
    __syncthreads();
  }

  #pragma unroll
  for (int qi = 0; qi < TQ; ++qi) {
    float rd[KNN]; int ri[KNN];
    #pragma unroll
    for (int r = 0; r < KNN; ++r) {
      float md = td0[qi]; int mi = ti0[qi];
      #pragma unroll
      for (int k = 1; k < 64; k <<= 1) {
        const float od = __shfl_xor(md, k);
        const int   oi = __shfl_xor(mi, k);
        if (pair_gt(od, oi, md, mi)) { md = od; mi = oi; }
      }
      rd[r] = md; ri[r] = mi;
      if (ti0[qi] == mi && td0[qi] == md) {
        td0[qi]=td1[qi]; ti0[qi]=ti1[qi];
        td1[qi]=td2[qi]; ti1[qi]=ti2[qi];
        td2[qi]=td3[qi]; ti2[qi]=ti3[qi];
        td3[qi]=td4[qi]; ti3[qi]=ti4[qi];
        td4[qi]=-1e30f;  ti4[qi]=0;
      }
    }
    if (lane == 0) {
      const int pbase = (q0 + qi) * (CH * KNN) + ci * KNN;
      #pragma unroll
      for (int r = 0; r < KNN; ++r) { pd[pbase + r] = rd[r]; pi[pbase + r] = ri[r]; }
    }
  }
}

// ---------------- Tier-3 fallback ----------------
__launch_bounds__(256)
__global__ void knn_fallback(const float* __restrict__ x,
                             const float* __restrict__ tg,
                             float* __restrict__ out, int N) {
  const int q   = blockIdx.x;
  const int tid = threadIdx.x;
  __shared__ float qsh[DD];
  __shared__ float smd[KNN][256];
  __shared__ int   smi[KNN][256];
  if (tid < DD) qsh[tid] = x[(size_t)q * DD + tid];
  __syncthreads();
  float qv[DD];
  #pragma unroll
  for (int d = 0; d < DD; ++d) qv[d] = qsh[d];
  float x2 = 0.0f;
  #pragma unroll
  for (int d = 0; d < DD; ++d) x2 = fmaf(qv[d], qv[d], x2);
  float a0=-1e30f,a1=-1e30f,a2=-1e30f,a3=-1e30f,a4=-1e30f;
  int   i0=0,i1=0,i2=0,i3=0,i4=0;
  for (int n = tid; n < N; n += 256) {
    const float4* tr = reinterpret_cast<const float4*>(tg + (size_t)n * DD);
    float dot = 0.0f, tt = 0.0f;
    #pragma unroll
    for (int k = 0; k < 16; ++k) {
      const float4 tv = tr[k];
      dot = fmaf(qv[4*k+0], tv.x, dot); tt = fmaf(tv.x, tv.x, tt);
      dot = fmaf(qv[4*k+1], tv.y, dot); tt = fmaf(tv.y, tv.y, tt);
      dot = fmaf(qv[4*k+2], tv.z, dot); tt = fmaf(tv.z, tv.z, tt);
      dot = fmaf(qv[4*k+3], tv.w, dot); tt = fmaf(tv.w, tv.w, tt);
    }
    const float d2 = fmaf(-2.0f, dot, x2 + tt);
    if (pair_gt(d2, n, a4, i4))
      top5_insert(d2, n, a0,a1,a2,a3,a4, i0,i1,i2,i3,i4);
  }
  smd[0][tid]=a0; smi[0][tid]=i0;  smd[1][tid]=a1; smi[1][tid]=i1;
  smd[2][tid]=a2; smi[2][tid]=i2;  smd[3][tid]=a3; smi[3][tid]=i3;
  smd[4][tid]=a4; smi[4][tid]=i4;
  __syncthreads();
  if (tid < 64) {
    a0=a1=a2=a3=a4=-1e30f; i0=i1=i2=i3=i4=0;
    for (int src = tid; src < 256; src += 64) {
      #pragma unroll
      for (int r = 0; r < KNN; ++r) {
        const float dd2 = smd[r][src]; const int ii = smi[r][src];
        if (pair_gt(dd2, ii, a4, i4))
          top5_insert(dd2, ii, a0,a1,a2,a3,a4, i0,i1,i2,i3,i4);
      }
    }
    int sel[KNN];
    #pragma unroll
    for (int r = 0; r < KNN; ++r) {
      float md = a0; int mi = i0;
      #pragma unroll
      for (int k = 1; k < 64; k <<= 1) {
        const float od = __shfl_xor(md, k);
        const int   oi = __shfl_xor(mi, k);
        if (pair_gt(od, oi, md, mi)) { md = od; mi = oi; }
      }
      sel[r] = mi;
      if (i0 == mi && a0 == md) {
        a0=a1; i0=i1; a1=a2; i1=i2; a2=a3; i2=i3; a3=a4; i3=i4; a4=-1e30f; i4=0;
      }
    }
    float s = 0.0f;
    #pragma unroll
    for (int r = 0; r < KNN; ++r) s += tg[(size_t)sel[r] * DD + tid];
    out[(size_t)q * DD + tid] = s / 5.0f;
  }
}

extern "C" void kernel_launch(void* const* d_in, const int* in_sizes, int n_in,
                              void* d_out, int out_size, void* d_ws, size_t ws_size,
                              hipStream_t stream) {
  const float* x  = (const float*)d_in[0];
  const float* tg = (const float*)d_in[1];
  float* out = (float*)d_out;
  const int B = in_sizes[0] / DD;   // 2048
  const int N = in_sizes[1] / DD;   // 50000

  // tier-1 configs: Npad multiple of CHN*GT*16 for fully uniform loops
  auto t1_need = [&](int chn, int& npad, int& tt, int& tiles) {
    const int align = chn * GT * NTT;
    npad  = ((N + align - 1) / align) * align;
    tt    = npad / NTT;
    tiles = tt / chn;
    return (size_t)npad * 4 + (size_t)B * chn * KNN * 8 + (size_t)tt * 4096;
  };
  int Npad64, TT64, tiles64, Npad32, TT32, tiles32;
  const size_t need64 = t1_need(64, Npad64, TT64, tiles64);
  const size_t need32 = t1_need(32, Npad32, TT32, tiles32);

  int CHN = 0, Npad = 0, TT = 0, tiles = 0, chnlog = 0;
  if (ws_size >= need64)      { CHN = 64; Npad = Npad64; TT = TT64; tiles = tiles64; chnlog = 6; }
  else if (ws_size >= need32) { CHN = 32; Npad = Npad32; TT = TT32; tiles = tiles32; chnlog = 5; }

  if (CHN > 0 && (B % QBB) == 0) {
    const size_t np1 = (size_t)B * CHN * KNN;
    float*          t2c  = (float*)d_ws;
    float*          pd   = t2c + Npad;
    int*            pi   = (int*)(pd + np1);
    unsigned short* tcvt = (unsigned short*)(pi + np1);
    sqnorm_chunked<<<dim3(Npad / 16), dim3(256), 0, stream>>>(tg, t2c, N, Npad, tiles, chnlog);
    cvt_kernel<<<dim3((TT + 3) / 4), dim3(256), 0, stream>>>(tg, tcvt, N, TT);
    knn_mfma_kernel<<<dim3(CHN, B / QBB), dim3(256), 0, stream>>>(x, tcvt, t2c, pd, pi, tiles, CHN);
    merge_kernel<<<dim3(B), dim3(64), 0, stream>>>(tg, pd, pi, out, CHN);
    return;
  }

  // tier-2
  const int    Npad_v    = (N + NT - 1) & ~(NT - 1);
  const size_t np2       = (size_t)B * CH * KNN;
  const size_t need_valu = ((size_t)Npad_v + 2 * np2) * 4;
  if (ws_size >= need_valu && (B % QB) == 0) {
    float* t2 = (float*)d_ws;
    float* pd = t2 + Npad_v;
    int*   pi = (int*)(pd + np2);
    sqnorm_kernel<<<dim3(Npad_v / 16), dim3(256), 0, stream>>>(tg, t2, N, Npad_v);
    knn_partial_kernel<<<dim3(CH, B / QB), dim3(BLK), 0, stream>>>(x, tg, t2, pd, pi, N);
    merge_kernel<<<dim3(B), dim3(64), 0, stream>>>(tg, pd, pi, out, CH);
  } else {
    knn_fallback<<<dim3(B), dim3(256), 0, stream>>>(x, tg, out, N);
  }
}